// Round 6
// baseline (507.893 us; speedup 1.0000x reference)
//
#include <hip/hip_runtime.h>
#include <hip/hip_bf16.h>

// Problem constants
#define BATCH 32
#define LQ 64
#define LD 512
#define EMB 300
#define FFH 100
#define ATTD 32
#define NH 8
#define NK 21
#define MQ (BATCH * LQ)          // 2048 query tokens
#define MD (BATCH * LD)          // 16384 doc tokens
#define MALL (MQ + MD)           // 18432 merged tokens

__device__ __forceinline__ float wave_sum(float v) {
    #pragma unroll
    for (int off = 32; off > 0; off >>= 1) v += __shfl_xor(v, off);
    return v;
}

// ---------------- elementwise: x = emb * mask(token) ----------------
__global__ void maskmul_kernel(const float* __restrict__ emb, const float* __restrict__ mask,
                               float* __restrict__ out, int n) {
    int i = blockIdx.x * blockDim.x + threadIdx.x;
    if (i < n) out[i] = emb[i] * mask[i / EMB];
}

// ---------------- mask concat: [mask_q | mask_d] -> maskall[18432] ----------------
__global__ void maskcat_kernel(const float* __restrict__ mq, const float* __restrict__ md,
                               float* __restrict__ out) {
    int i = blockIdx.x * blockDim.x + threadIdx.x;
    if (i < MALL) out[i] = (i < MQ) ? mq[i] : md[i - MQ];
}

// ---------------- tiled GEMM v3: 64x64 tile, 4x4 micro-tile, double-buffered LDS,
//                  register prefetch, 1 barrier per K-step.
// C[M,N] = A[M,K] @ B[K,N] + bias (+relu / +residual)
// EPI: 0 = bias, 1 = bias+relu, 2 = bias+residual
// As padded to 68 (2-way store conflict = free); Bs 64 (2-way read = free).
// M must be a multiple of 64; N,K arbitrary.
template <int EPI>
__global__ __launch_bounds__(256) void gemm_nn(const float* __restrict__ A, const float* __restrict__ Bw,
                                               const float* __restrict__ bias, const float* __restrict__ R,
                                               float* __restrict__ C, int M, int N, int K) {
    __shared__ __align__(16) float As[2][16][68];   // [buf][k][m]
    __shared__ __align__(16) float Bs[2][16][64];   // [buf][k][n]
    const int tid = threadIdx.x;
    const int m0 = blockIdx.y * 64, n0 = blockIdx.x * 64;
    const int tr = tid >> 4, tc = tid & 15;         // micro-tile coords
    const int rA = tid >> 2, kA = (tid & 3) * 4;    // A staging: 64 rows x 16 k
    const bool nfull = (n0 + 64 <= N);
    const int NS = (K + 15) >> 4;

    float acc[4][4] = {};
    float4 av, bv;

#define GEMM_LOAD(K0)                                                           \
    {                                                                           \
        const int k0_ = (K0);                                                   \
        int kk = k0_ + kA;                                                      \
        const float* arow = A + (size_t)(m0 + rA) * K + kk;                     \
        if (kk + 4 <= K) av = *(const float4*)arow;                             \
        else {                                                                  \
            av.x = (kk     < K) ? arow[0] : 0.f;                                \
            av.y = (kk + 1 < K) ? arow[1] : 0.f;                                \
            av.z = (kk + 2 < K) ? arow[2] : 0.f;                                \
            av.w = (kk + 3 < K) ? arow[3] : 0.f;                                \
        }                                                                       \
        int kb = k0_ + tr;                                                      \
        bv.x = bv.y = bv.z = bv.w = 0.f;                                        \
        if (kb < K) {                                                           \
            const float* brow = Bw + (size_t)kb * N + n0 + tc * 4;              \
            if (nfull) bv = *(const float4*)brow;                               \
            else {                                                              \
                int n = n0 + tc * 4;                                            \
                if (n     < N) bv.x = brow[0];                                  \
                if (n + 1 < N) bv.y = brow[1];                                  \
                if (n + 2 < N) bv.z = brow[2];                                  \
                if (n + 3 < N) bv.w = brow[3];                                  \
            }                                                                   \
        }                                                                       \
    }

#define GEMM_STORE_LDS(BUF)                                                     \
    {                                                                           \
        const int b_ = (BUF);                                                   \
        As[b_][kA + 0][rA] = av.x;                                              \
        As[b_][kA + 1][rA] = av.y;                                              \
        As[b_][kA + 2][rA] = av.z;                                              \
        As[b_][kA + 3][rA] = av.w;                                              \
        *(float4*)&Bs[b_][tr][tc * 4] = bv;                                     \
    }

    GEMM_LOAD(0)
    GEMM_STORE_LDS(0)
    __syncthreads();

    for (int s = 0; s < NS; s++) {
        const int cur = s & 1;
        const bool more = (s + 1 < NS);
        if (more) GEMM_LOAD((s + 1) << 4)
        #pragma unroll
        for (int kk = 0; kk < 16; kk++) {
            float4 a4 = *(const float4*)&As[cur][kk][tr * 4];
            float4 b4 = *(const float4*)&Bs[cur][kk][tc * 4];
            float avr[4] = {a4.x, a4.y, a4.z, a4.w};
            float bvr[4] = {b4.x, b4.y, b4.z, b4.w};
            #pragma unroll
            for (int i = 0; i < 4; i++)
                #pragma unroll
                for (int j = 0; j < 4; j++) acc[i][j] = fmaf(avr[i], bvr[j], acc[i][j]);
        }
        if (more) GEMM_STORE_LDS(cur ^ 1)
        __syncthreads();
    }
#undef GEMM_LOAD
#undef GEMM_STORE_LDS

    // epilogue
    const int col = n0 + tc * 4;
    float4 bias4 = {0.f, 0.f, 0.f, 0.f};
    if (nfull) bias4 = *(const float4*)(bias + col);
    else {
        if (col     < N) bias4.x = bias[col];
        if (col + 1 < N) bias4.y = bias[col + 1];
        if (col + 2 < N) bias4.z = bias[col + 2];
        if (col + 3 < N) bias4.w = bias[col + 3];
    }
    #pragma unroll
    for (int i = 0; i < 4; i++) {
        int row = m0 + tr * 4 + i;
        float4 v;
        v.x = acc[i][0] + bias4.x;
        v.y = acc[i][1] + bias4.y;
        v.z = acc[i][2] + bias4.z;
        v.w = acc[i][3] + bias4.w;
        if (EPI == 1) {
            v.x = fmaxf(v.x, 0.f); v.y = fmaxf(v.y, 0.f);
            v.z = fmaxf(v.z, 0.f); v.w = fmaxf(v.w, 0.f);
        }
        if (EPI == 2) {
            const float* rrow = R + (size_t)row * N + col;
            if (nfull) {
                float4 r4 = *(const float4*)rrow;
                v.x += r4.x; v.y += r4.y; v.z += r4.z; v.w += r4.w;
            } else {
                if (col     < N) v.x += rrow[0];
                if (col + 1 < N) v.y += rrow[1];
                if (col + 2 < N) v.z += rrow[2];
                if (col + 3 < N) v.w += rrow[3];
            }
        }
        float* crow = C + (size_t)row * N + col;
        if (nfull) {
            *(float4*)crow = v;
        } else {
            if (col     < N) crow[0] = v.x;
            if (col + 1 < N) crow[1] = v.y;
            if (col + 2 < N) crow[2] = v.z;
            if (col + 3 < N) crow[3] = v.w;
        }
    }
}

// ---------------- LayerNorm (ddof=1, eps added to std), one wave per token (300 elems) ------
__global__ __launch_bounds__(256) void ln_kernel(const float* __restrict__ X, const float* __restrict__ g,
                                                 const float* __restrict__ bta, float* __restrict__ Y, int M) {
    int wid = (blockIdx.x * 256 + threadIdx.x) >> 6;
    int lane = threadIdx.x & 63;
    if (wid >= M) return;
    const float* x = X + (size_t)wid * EMB;
    float v[5];
    float s = 0.f;
    #pragma unroll
    for (int r = 0; r < 5; r++) {
        int idx = lane + r * 64;
        float val = (idx < EMB) ? x[idx] : 0.f;
        v[r] = val;
        s += val;
    }
    s = wave_sum(s);
    float mean = s * (1.f / EMB);
    float s2 = 0.f;
    #pragma unroll
    for (int r = 0; r < 5; r++) {
        int idx = lane + r * 64;
        if (idx < EMB) { float d = v[r] - mean; s2 += d * d; }
    }
    s2 = wave_sum(s2);
    float stdv = sqrtf(s2 * (1.f / (EMB - 1)));
    float inv = 1.f / (stdv + 1e-6f);
    float* y = Y + (size_t)wid * EMB;
    #pragma unroll
    for (int r = 0; r < 5; r++) {
        int idx = lane + r * 64;
        if (idx < EMB) y[idx] = g[idx] * (v[r] - mean) * inv + bta[idx];
    }
}

// ---------------- attention: single-pass (no max), premasked K/V in LDS, k-split ---------
// c layout: [tokens, 96]  (q | k | v, each 32 = 8 heads * 4)
template <int T, int RPB, int KS>
__global__ __launch_bounds__(512) void attn_fused(const float* __restrict__ c,
                                                  const float* __restrict__ mask,
                                                  float* __restrict__ o32) {
    constexpr int BLK = RPB * KS;
    constexpr int NRB = T / RPB;
    __shared__ float4 Ks[T];
    __shared__ float4 Vs[T];
    __shared__ float part[RPB * 5 * (KS - 1)];
    __shared__ float nmask_s;
    const int bh = blockIdx.x / NRB;
    const int rb = blockIdx.x % NRB;
    const int b = bh / NH, h = bh % NH;
    const int tid = threadIdx.x;
    const float* base = c + (size_t)b * T * 96;

    if (tid == 0) nmask_s = 0.f;
    __syncthreads();
    float lnm = 0.f;
    for (int j = tid; j < T; j += BLK) {
        float m = mask[b * T + j];
        float4 kv = *(const float4*)(base + (size_t)j * 96 + ATTD + h * 4);
        float4 vv = *(const float4*)(base + (size_t)j * 96 + 2 * ATTD + h * 4);
        kv.x *= m; kv.y *= m; kv.z *= m; kv.w *= m;
        vv.x *= m; vv.y *= m; vv.z *= m; vv.w *= m;
        Ks[j] = kv;
        Vs[j] = vv;
        lnm += 1.f - m;
    }
    lnm = wave_sum(lnm);
    if ((tid & 63) == 0 && lnm != 0.f) atomicAdd(&nmask_s, lnm);
    __syncthreads();

    const int r = rb * RPB + (tid % RPB);
    const int ks = tid / RPB;
    const float inv_scale = 0.16439898730535729f;  // 1/sqrt(37)
    float4 qv = *(const float4*)(base + (size_t)r * 96 + h * 4);
    qv.x *= inv_scale; qv.y *= inv_scale; qv.z *= inv_scale; qv.w *= inv_scale;

    float Sall = 0.f, ox = 0.f, oy = 0.f, oz = 0.f, ow = 0.f;
    constexpr int KC = T / KS;
    const int k0 = ks * KC;
    #pragma unroll 4
    for (int k = k0; k < k0 + KC; k++) {
        float4 kv = Ks[k];
        float4 vv = Vs[k];
        float s = fmaf(qv.x, kv.x, fmaf(qv.y, kv.y, fmaf(qv.z, kv.z, qv.w * kv.w)));
        float e = __expf(s);
        Sall += e;
        ox = fmaf(e, vv.x, ox);
        oy = fmaf(e, vv.y, oy);
        oz = fmaf(e, vv.z, oz);
        ow = fmaf(e, vv.w, ow);
    }
    if (ks > 0) {
        float* p = &part[((ks - 1) * RPB + (tid % RPB)) * 5];
        p[0] = Sall; p[1] = ox; p[2] = oy; p[3] = oz; p[4] = ow;
    }
    __syncthreads();
    if (ks == 0) {
        #pragma unroll
        for (int s2 = 0; s2 < KS - 1; s2++) {
            const float* p = &part[(s2 * RPB + r - rb * RPB) * 5];
            Sall += p[0]; ox += p[1]; oy += p[2]; oz += p[3]; ow += p[4];
        }
        float Sm = Sall - nmask_s;
        float inv = 1.f / (Sm + 1e-13f * Sall);
        float4 o = {ox * inv, oy * inv, oz * inv, ow * inv};
        *(float4*)(o32 + (size_t)(b * T + r) * ATTD + h * 4) = o;
    }
}

// ---------------- mix + L2 normalize: one wave per token (merged stream) ----------------
__global__ __launch_bounds__(256) void mixnorm_kernel(const float* __restrict__ x, const float* __restrict__ xc,
                                                      const float* __restrict__ mask, const float* __restrict__ mixer,
                                                      float* __restrict__ out) {
    int wid = (blockIdx.x * 256 + threadIdx.x) >> 6;
    int lane = threadIdx.x & 63;
    float mixv = mixer[0];
    float mval = mask[wid];
    const float* xr = x + (size_t)wid * EMB;
    const float* xcr = xc + (size_t)wid * EMB;
    float v[5];
    float s2 = 0.f;
    #pragma unroll
    for (int r = 0; r < 5; r++) {
        int idx = lane + r * 64;
        float val = 0.f;
        if (idx < EMB) val = (mixv * xr[idx] + (1.f - mixv) * xcr[idx]) * mval;
        v[r] = val;
        s2 += val * val;
    }
    s2 = wave_sum(s2);
    float inv = 1.f / (sqrtf(s2) + 1e-13f);
    float* o = out + (size_t)wid * EMB;
    #pragma unroll
    for (int r = 0; r < 5; r++) {
        int idx = lane + r * 64;
        if (idx < EMB) o[idx] = v[r] * inv;
    }
}

// ---------------- batched NT GEMM: cos[b] = qn[b] (64x300) @ dn[b]^T (300x512) ----------------
__global__ __launch_bounds__(256) void gemm_nt_cos(const float* __restrict__ Qn, const float* __restrict__ Dn,
                                                   float* __restrict__ Cos) {
    int b = blockIdx.y;
    int n0 = blockIdx.x * 64;
    const float* A = Qn + (size_t)b * LQ * EMB;
    const float* Bm = Dn + (size_t)b * LD * EMB;
    __shared__ __align__(16) float As[16][68];
    __shared__ __align__(16) float Bs[16][68];
    const int tid = threadIdx.x;
    const int tr = tid >> 4, tc = tid & 15;
    float acc[4][4] = {};
    for (int k0 = 0; k0 < EMB; k0 += 16) {
        #pragma unroll
        for (int i = 0; i < 4; i++) {
            int idx = tid + i * 256;
            int r = idx >> 4, cl = idx & 15;
            int kk = k0 + cl;
            As[cl][r] = (kk < EMB) ? A[(size_t)r * EMB + kk] : 0.f;
            Bs[cl][r] = (kk < EMB) ? Bm[(size_t)(n0 + r) * EMB + kk] : 0.f;
        }
        __syncthreads();
        #pragma unroll
        for (int kk = 0; kk < 16; kk++) {
            float4 a4 = *(const float4*)&As[kk][tr * 4];
            float4 b4 = *(const float4*)&Bs[kk][tc * 4];
            float av[4] = {a4.x, a4.y, a4.z, a4.w};
            float bv[4] = {b4.x, b4.y, b4.z, b4.w};
            #pragma unroll
            for (int i = 0; i < 4; i++)
                #pragma unroll
                for (int j = 0; j < 4; j++) acc[i][j] += av[i] * bv[j];
        }
        __syncthreads();
    }
    #pragma unroll
    for (int i = 0; i < 4; i++) {
        int row = tr * 4 + i;
        #pragma unroll
        for (int j = 0; j < 4; j++) {
            int col = n0 + tc * 4 + j;
            Cos[(size_t)b * LQ * LD + (size_t)row * LD + col] = acc[i][j];
        }
    }
}

// ---------------- kernel pooling: one wave per (b, qi); 21 RBF kernels ----------------
__global__ __launch_bounds__(256) void pool_kernel(const float* __restrict__ Cos, const float* __restrict__ mask_q,
                                                   const float* __restrict__ mask_d, const float* __restrict__ nn_scaler,
                                                   float* __restrict__ lp) {
    int wid = (blockIdx.x * 256 + threadIdx.x) >> 6;
    int lane = threadIdx.x & 63;
    int b = wid >> 6, qi = wid & 63;
    const float* crow = Cos + ((size_t)b * LQ + qi) * LD;
    const float* md = mask_d + b * LD;
    float acc[NK];
    #pragma unroll
    for (int k = 0; k < NK; k++) acc[k] = 0.f;
    #pragma unroll
    for (int r = 0; r < LD / 64; r++) {
        int dj = r * 64 + lane;
        float m = md[dj];
        if (m != 0.f) {
            float cv = crow[dj];
            #pragma unroll
            for (int k = 0; k < NK; k++) {
                float mu = (k == 0) ? 1.0f : (0.95f - 0.1f * (k - 1));
                float neg_inv = (k == 0) ? -500000.0f : -50.0f;
                float d = cv - mu;
                acc[k] += expf(d * d * neg_inv);
            }
        }
    }
    float mq = mask_q[b * LQ + qi];
    float ns = nn_scaler[0];
    #pragma unroll
    for (int k = 0; k < NK; k++) {
        float s = wave_sum(acc[k]);
        if (lane == 0) lp[((size_t)b * LQ + qi) * NK + k] = log2f(fmaxf(s, 1e-10f)) * ns * mq;
    }
}

// ---------------- final: out[b] = sum_k dense_w[k] * sum_qi lp[b,qi,k] ----------------
__global__ void final_kernel(const float* __restrict__ lp, const float* __restrict__ dense_w,
                             float* __restrict__ out) {
    int b = blockIdx.x;
    int t = threadIdx.x;  // 64 threads
    float s = 0.f;
    if (t < NK) {
        for (int qi = 0; qi < LQ; qi++) s += lp[((size_t)b * LQ + qi) * NK + t];
        s *= dense_w[t];
    }
    s = wave_sum(s);
    if (t == 0) out[b] = s;
}

extern "C" void kernel_launch(void* const* d_in, const int* in_sizes, int n_in,
                              void* d_out, int out_size, void* d_ws, size_t ws_size,
                              hipStream_t stream) {
    (void)in_sizes; (void)n_in; (void)out_size; (void)ws_size;
    const float* q_embed  = (const float*)d_in[0];
    const float* d_embed  = (const float*)d_in[1];
    const float* mask_q   = (const float*)d_in[2];
    const float* mask_d   = (const float*)d_in[3];
    const float* mixer    = (const float*)d_in[4];
    const float* nn_scaler= (const float*)d_in[5];
    const float* ff_w1    = (const float*)d_in[6];
    const float* ff_b1    = (const float*)d_in[7];
    const float* ff_w2    = (const float*)d_in[8];
    const float* ff_b2    = (const float*)d_in[9];
    const float* ln1_g    = (const float*)d_in[10];
    const float* ln1_b    = (const float*)d_in[11];
    const float* att_w    = (const float*)d_in[12];
    const float* att_b    = (const float*)d_in[13];
    const float* out_w    = (const float*)d_in[14];
    const float* out_b    = (const float*)d_in[15];
    const float* ln2_g    = (const float*)d_in[16];
    const float* ln2_b    = (const float*)d_in[17];
    const float* dense_w  = (const float*)d_in[18];
    float* out = (float*)d_out;

    // workspace layout (floats) — merged token stream: [q tokens (2048) | d tokens (16384)]
    float* ws   = (float*)d_ws;
    float* x    = ws;                      // MALL*300 = 5,529,600 (masked embeddings, persists)
    float* xc   = x   + (size_t)MALL * EMB; // 5,529,600 (encoder output / layer chain)
    float* t2   = xc  + (size_t)MALL * EMB; // 5,529,600
    float* hb   = t2  + (size_t)MALL * EMB; // 5,529,600
    float* t1cb = hb  + (size_t)MALL * EMB; // max(MALL*100, MALL*96) = 1,843,200
    float* o32  = t1cb + (size_t)MALL * FFH; // MALL*32 = 589,824
    float* mall = o32 + (size_t)MALL * ATTD; // 18,432
    // post-encoder aliases:
    float* qdn  = t2;                      // mixed+normalized tokens
    float* cosb = hb;                      // 32*64*512 = 1,048,576
    float* lp   = o32;                     // 32*64*21

    // 1. masked inputs (q segment then d segment) + mask concat
    maskmul_kernel<<<(MQ * EMB + 255) / 256, 256, 0, stream>>>(q_embed, mask_q, x, MQ * EMB);
    maskmul_kernel<<<(MD * EMB + 255) / 256, 256, 0, stream>>>(d_embed, mask_d, x + (size_t)MQ * EMB, MD * EMB);
    maskcat_kernel<<<(MALL + 255) / 256, 256, 0, stream>>>(mask_q, mask_d, mall);

    // 2. merged encoder (q+d share weights; attention splits by segment)
    const float* xcur = x;
    for (int l = 0; l < 2; l++) {
        gemm_nn<1><<<dim3(2, MALL / 64), 256, 0, stream>>>(xcur, ff_w1 + l * EMB * FFH, ff_b1 + l * FFH,
                                                           nullptr, t1cb, MALL, FFH, EMB);
        gemm_nn<2><<<dim3(5, MALL / 64), 256, 0, stream>>>(t1cb, ff_w2 + l * FFH * EMB, ff_b2 + l * EMB,
                                                           xcur, t2, MALL, EMB, FFH);
        ln_kernel<<<MALL / 4, 256, 0, stream>>>(t2, ln1_g + l * EMB, ln1_b + l * EMB, hb, MALL);
        gemm_nn<0><<<dim3(2, MALL / 64), 256, 0, stream>>>(hb, att_w + l * EMB * 96, att_b + l * 96,
                                                           nullptr, t1cb, MALL, 96, EMB);
        attn_fused<LQ, 64, 8><<<BATCH * NH, 512, 0, stream>>>(t1cb, mask_q, o32);
        attn_fused<LD, 128, 4><<<BATCH * NH * (LD / 128), 512, 0, stream>>>(
            t1cb + (size_t)MQ * 96, mask_d, o32 + (size_t)MQ * ATTD);
        gemm_nn<2><<<dim3(5, MALL / 64), 256, 0, stream>>>(o32, out_w + l * ATTD * EMB, out_b + l * EMB,
                                                           hb, t2, MALL, EMB, ATTD);
        ln_kernel<<<MALL / 4, 256, 0, stream>>>(t2, ln2_g + l * EMB, ln2_b + l * EMB, xc, MALL);
        xcur = xc;
    }

    // 3. mix + normalize (merged)
    mixnorm_kernel<<<MALL / 4, 256, 0, stream>>>(x, xc, mall, mixer, qdn);

    // 4. cosine matrix (q segment vs d segment of qdn)
    gemm_nt_cos<<<dim3(LD / 64, BATCH), 256, 0, stream>>>(qdn, qdn + (size_t)MQ * EMB, cosb);

    // 5. kernel pooling
    pool_kernel<<<(BATCH * LQ) / 4, 256, 0, stream>>>(cosb, mask_q, mask_d, nn_scaler, lp);

    // 6. final projection
    final_kernel<<<BATCH, 64, 0, stream>>>(lp, dense_w, out);
}

// Round 7
// 327.910 us; speedup vs baseline: 1.5489x; 1.5489x over previous
//
#include <hip/hip_runtime.h>
#include <hip/hip_bf16.h>

// Problem constants
#define BATCH 32
#define LQ 64
#define LD 512
#define EMB 300
#define FFH 100
#define ATTD 32
#define NH 8
#define NK 21
#define MQ (BATCH * LQ)          // 2048 query tokens
#define MD (BATCH * LD)          // 16384 doc tokens
#define MALL (MQ + MD)           // 18432 merged tokens

typedef __attribute__((ext_vector_type(8))) short bf16x8;
typedef __attribute__((ext_vector_type(4))) float f32x4;

__device__ __forceinline__ float wave_sum(float v) {
    #pragma unroll
    for (int off = 32; off > 0; off >>= 1) v += __shfl_xor(v, off);
    return v;
}

// ---------------- elementwise: x = emb * mask(token), fp32 + bf16 copies ----------------
__global__ void maskmul_kernel(const float* __restrict__ emb, const float* __restrict__ mask,
                               float* __restrict__ out, __hip_bfloat16* __restrict__ outb, int n) {
    int i = blockIdx.x * blockDim.x + threadIdx.x;
    if (i < n) {
        float v = emb[i] * mask[i / EMB];
        out[i] = v;
        outb[i] = __float2bfloat16(v);
    }
}

// ---------------- mask concat: [mask_q | mask_d] -> maskall[18432] ----------------
__global__ void maskcat_kernel(const float* __restrict__ mq, const float* __restrict__ md,
                               float* __restrict__ out) {
    int i = blockIdx.x * blockDim.x + threadIdx.x;
    if (i < MALL) out[i] = (i < MQ) ? mq[i] : md[i - MQ];
}

// ---------------- weight convert + transpose: w[L][K][N] fp32 -> wt[L][N][K] bf16 ----------
__global__ void convert_wt(const float* __restrict__ w, __hip_bfloat16* __restrict__ wt,
                           int L, int K, int N) {
    int i = blockIdx.x * blockDim.x + threadIdx.x;
    int tot = L * K * N;
    if (i >= tot) return;
    int l = i / (K * N);
    int r = i % (K * N);
    int k = r / N, n = r % N;
    wt[(size_t)l * N * K + (size_t)n * K + k] = __float2bfloat16(w[i]);
}

// ---------------- MFMA bf16 GEMM: C[M,N] = A[M,K] @ Bt[N,K]^T + bias (+relu/+res) --------
// A row-major bf16 [M][K]; Bt = B transposed, row-major bf16 [N][K].
// 64x64 tile, 4 waves (2x2), each wave 32x32 via 2x2 mfma_f32_16x16x32_bf16 fragments.
// LDS [64][40] bf16 padded (frag reads ~2-way conflict = free).
// k-sets per lane-group identical for A and B loads -> layout-permutation safe.
// D layout (m89-verified): col = lane&15, row = (lane>>4)*4 + reg.
__device__ __forceinline__ void stage_row8(const __hip_bfloat16* __restrict__ src, bool rowvalid,
                                           int K, int gk, __hip_bfloat16* dst) {
    if (rowvalid && gk + 8 <= K) {
        const uint2* p = (const uint2*)(src + gk);   // 8B-aligned (K even, gk%8==0)
        uint2 a = p[0], b = p[1];
        *(uint2*)dst = a;
        *(uint2*)(dst + 4) = b;
    } else {
        #pragma unroll
        for (int j = 0; j < 8; j++)
            dst[j] = (rowvalid && gk + j < K) ? src[gk + j] : __float2bfloat16(0.f);
    }
}

template <bool RELU, bool HAS_RES, bool BF16OUT>
__global__ __launch_bounds__(256) void gemm_mfma(const __hip_bfloat16* __restrict__ A,
                                                 const __hip_bfloat16* __restrict__ Bt,
                                                 const float* __restrict__ bias,
                                                 const float* __restrict__ Rres,
                                                 float* __restrict__ C,
                                                 __hip_bfloat16* __restrict__ Cb,
                                                 int M, int N, int K) {
    __shared__ __align__(16) __hip_bfloat16 As[64][40];
    __shared__ __align__(16) __hip_bfloat16 Bs[64][40];
    const int tid = threadIdx.x;
    const int m0 = blockIdx.y * 64, n0 = blockIdx.x * 64;
    const int lane = tid & 63;
    const int wv = tid >> 6;
    const int wm = wv >> 1, wn = wv & 1;
    const int l15 = lane & 15, lg = lane >> 4;
    const int srow = tid >> 2, sk8 = (tid & 3) * 8;
    f32x4 acc[2][2] = {};
    const int NS = (K + 31) >> 5;
    const __hip_bfloat16* arow = A + (size_t)(m0 + srow) * K;
    const bool bvalid = (n0 + srow) < N;
    const __hip_bfloat16* brow = Bt + (size_t)(n0 + srow) * K;

    for (int s = 0; s < NS; s++) {
        const int gk = (s << 5) + sk8;
        if (s) __syncthreads();
        stage_row8(arow, true, K, gk, &As[srow][sk8]);
        stage_row8(brow, bvalid, K, gk, &Bs[srow][sk8]);
        __syncthreads();
        bf16x8 af0 = *(const bf16x8*)&As[wm * 32 + l15][lg * 8];
        bf16x8 af1 = *(const bf16x8*)&As[wm * 32 + 16 + l15][lg * 8];
        bf16x8 bf0 = *(const bf16x8*)&Bs[wn * 32 + l15][lg * 8];
        bf16x8 bf1 = *(const bf16x8*)&Bs[wn * 32 + 16 + l15][lg * 8];
        acc[0][0] = __builtin_amdgcn_mfma_f32_16x16x32_bf16(af0, bf0, acc[0][0], 0, 0, 0);
        acc[0][1] = __builtin_amdgcn_mfma_f32_16x16x32_bf16(af0, bf1, acc[0][1], 0, 0, 0);
        acc[1][0] = __builtin_amdgcn_mfma_f32_16x16x32_bf16(af1, bf0, acc[1][0], 0, 0, 0);
        acc[1][1] = __builtin_amdgcn_mfma_f32_16x16x32_bf16(af1, bf1, acc[1][1], 0, 0, 0);
    }

    #pragma unroll
    for (int fc = 0; fc < 2; fc++) {
        int col = n0 + wn * 32 + fc * 16 + l15;
        if (col >= N) continue;
        float bs = bias[col];
        #pragma unroll
        for (int fr = 0; fr < 2; fr++) {
            int rbase = m0 + wm * 32 + fr * 16 + lg * 4;
            #pragma unroll
            for (int r = 0; r < 4; r++) {
                int row = rbase + r;
                float v = acc[fr][fc][r] + bs;
                if (RELU) v = fmaxf(v, 0.f);
                size_t idx = (size_t)row * N + col;
                if (HAS_RES) v += Rres[idx];
                if (BF16OUT) Cb[idx] = __float2bfloat16(v);
                else C[idx] = v;
            }
        }
    }
}

// ---------------- LayerNorm (ddof=1, eps added to std); optional bf16 copy ----------------
template <bool EMITB>
__global__ __launch_bounds__(256) void ln_kernel(const float* __restrict__ X, const float* __restrict__ g,
                                                 const float* __restrict__ bta, float* __restrict__ Y,
                                                 __hip_bfloat16* __restrict__ Yb, int M) {
    int wid = (blockIdx.x * 256 + threadIdx.x) >> 6;
    int lane = threadIdx.x & 63;
    if (wid >= M) return;
    const float* x = X + (size_t)wid * EMB;
    float v[5];
    float s = 0.f;
    #pragma unroll
    for (int r = 0; r < 5; r++) {
        int idx = lane + r * 64;
        float val = (idx < EMB) ? x[idx] : 0.f;
        v[r] = val;
        s += val;
    }
    s = wave_sum(s);
    float mean = s * (1.f / EMB);
    float s2 = 0.f;
    #pragma unroll
    for (int r = 0; r < 5; r++) {
        int idx = lane + r * 64;
        if (idx < EMB) { float d = v[r] - mean; s2 += d * d; }
    }
    s2 = wave_sum(s2);
    float stdv = sqrtf(s2 * (1.f / (EMB - 1)));
    float inv = 1.f / (stdv + 1e-6f);
    float* y = Y + (size_t)wid * EMB;
    __hip_bfloat16* yb = EMITB ? (Yb + (size_t)wid * EMB) : nullptr;
    #pragma unroll
    for (int r = 0; r < 5; r++) {
        int idx = lane + r * 64;
        if (idx < EMB) {
            float val = g[idx] * (v[r] - mean) * inv + bta[idx];
            y[idx] = val;
            if (EMITB) yb[idx] = __float2bfloat16(val);
        }
    }
}

// ---------------- attention: single-pass (no max), premasked K/V in LDS, k-split ---------
// c layout: [tokens, 96]  (q | k | v, each 32 = 8 heads * 4). Output bf16.
template <int T, int RPB, int KS>
__global__ __launch_bounds__(512) void attn_fused(const float* __restrict__ c,
                                                  const float* __restrict__ mask,
                                                  __hip_bfloat16* __restrict__ o32) {
    constexpr int BLK = RPB * KS;
    constexpr int NRB = T / RPB;
    __shared__ float4 Ks[T];
    __shared__ float4 Vs[T];
    __shared__ float part[RPB * 5 * (KS - 1)];
    __shared__ float nmask_s;
    const int bh = blockIdx.x / NRB;
    const int rb = blockIdx.x % NRB;
    const int b = bh / NH, h = bh % NH;
    const int tid = threadIdx.x;
    const float* base = c + (size_t)b * T * 96;

    if (tid == 0) nmask_s = 0.f;
    __syncthreads();
    float lnm = 0.f;
    for (int j = tid; j < T; j += BLK) {
        float m = mask[b * T + j];
        float4 kv = *(const float4*)(base + (size_t)j * 96 + ATTD + h * 4);
        float4 vv = *(const float4*)(base + (size_t)j * 96 + 2 * ATTD + h * 4);
        kv.x *= m; kv.y *= m; kv.z *= m; kv.w *= m;
        vv.x *= m; vv.y *= m; vv.z *= m; vv.w *= m;
        Ks[j] = kv;
        Vs[j] = vv;
        lnm += 1.f - m;
    }
    lnm = wave_sum(lnm);
    if ((tid & 63) == 0 && lnm != 0.f) atomicAdd(&nmask_s, lnm);
    __syncthreads();

    const int r = rb * RPB + (tid % RPB);
    const int ks = tid / RPB;
    const float inv_scale = 0.16439898730535729f;  // 1/sqrt(37)
    float4 qv = *(const float4*)(base + (size_t)r * 96 + h * 4);
    qv.x *= inv_scale; qv.y *= inv_scale; qv.z *= inv_scale; qv.w *= inv_scale;

    float Sall = 0.f, ox = 0.f, oy = 0.f, oz = 0.f, ow = 0.f;
    constexpr int KC = T / KS;
    const int k0 = ks * KC;
    #pragma unroll 4
    for (int k = k0; k < k0 + KC; k++) {
        float4 kv = Ks[k];
        float4 vv = Vs[k];
        float s = fmaf(qv.x, kv.x, fmaf(qv.y, kv.y, fmaf(qv.z, kv.z, qv.w * kv.w)));
        float e = __expf(s);
        Sall += e;
        ox = fmaf(e, vv.x, ox);
        oy = fmaf(e, vv.y, oy);
        oz = fmaf(e, vv.z, oz);
        ow = fmaf(e, vv.w, ow);
    }
    if (ks > 0) {
        float* p = &part[((ks - 1) * RPB + (tid % RPB)) * 5];
        p[0] = Sall; p[1] = ox; p[2] = oy; p[3] = oz; p[4] = ow;
    }
    __syncthreads();
    if (ks == 0) {
        #pragma unroll
        for (int s2 = 0; s2 < KS - 1; s2++) {
            const float* p = &part[(s2 * RPB + r - rb * RPB) * 5];
            Sall += p[0]; ox += p[1]; oy += p[2]; oz += p[3]; ow += p[4];
        }
        float Sm = Sall - nmask_s;
        float inv = 1.f / (Sm + 1e-13f * Sall);
        __hip_bfloat16* op = o32 + (size_t)(b * T + r) * ATTD + h * 4;
        op[0] = __float2bfloat16(ox * inv);
        op[1] = __float2bfloat16(oy * inv);
        op[2] = __float2bfloat16(oz * inv);
        op[3] = __float2bfloat16(ow * inv);
    }
}

// ---------------- mix + L2 normalize: one wave per token (merged stream) ----------------
__global__ __launch_bounds__(256) void mixnorm_kernel(const float* __restrict__ x, const float* __restrict__ xc,
                                                      const float* __restrict__ mask, const float* __restrict__ mixer,
                                                      float* __restrict__ out) {
    int wid = (blockIdx.x * 256 + threadIdx.x) >> 6;
    int lane = threadIdx.x & 63;
    float mixv = mixer[0];
    float mval = mask[wid];
    const float* xr = x + (size_t)wid * EMB;
    const float* xcr = xc + (size_t)wid * EMB;
    float v[5];
    float s2 = 0.f;
    #pragma unroll
    for (int r = 0; r < 5; r++) {
        int idx = lane + r * 64;
        float val = 0.f;
        if (idx < EMB) val = (mixv * xr[idx] + (1.f - mixv) * xcr[idx]) * mval;
        v[r] = val;
        s2 += val * val;
    }
    s2 = wave_sum(s2);
    float inv = 1.f / (sqrtf(s2) + 1e-13f);
    float* o = out + (size_t)wid * EMB;
    #pragma unroll
    for (int r = 0; r < 5; r++) {
        int idx = lane + r * 64;
        if (idx < EMB) o[idx] = v[r] * inv;
    }
}

// ---------------- batched NT GEMM: cos[b] = qn[b] (64x300) @ dn[b]^T (300x512), fp32 --------
__global__ __launch_bounds__(256) void gemm_nt_cos(const float* __restrict__ Qn, const float* __restrict__ Dn,
                                                   float* __restrict__ Cos) {
    int b = blockIdx.y;
    int n0 = blockIdx.x * 64;
    const float* A = Qn + (size_t)b * LQ * EMB;
    const float* Bm = Dn + (size_t)b * LD * EMB;
    __shared__ __align__(16) float As[16][68];
    __shared__ __align__(16) float Bs[16][68];
    const int tid = threadIdx.x;
    const int tr = tid >> 4, tc = tid & 15;
    float acc[4][4] = {};
    for (int k0 = 0; k0 < EMB; k0 += 16) {
        #pragma unroll
        for (int i = 0; i < 4; i++) {
            int idx = tid + i * 256;
            int r = idx >> 4, cl = idx & 15;
            int kk = k0 + cl;
            As[cl][r] = (kk < EMB) ? A[(size_t)r * EMB + kk] : 0.f;
            Bs[cl][r] = (kk < EMB) ? Bm[(size_t)(n0 + r) * EMB + kk] : 0.f;
        }
        __syncthreads();
        #pragma unroll
        for (int kk = 0; kk < 16; kk++) {
            float4 a4 = *(const float4*)&As[kk][tr * 4];
            float4 b4 = *(const float4*)&Bs[kk][tc * 4];
            float av[4] = {a4.x, a4.y, a4.z, a4.w};
            float bv[4] = {b4.x, b4.y, b4.z, b4.w};
            #pragma unroll
            for (int i = 0; i < 4; i++)
                #pragma unroll
                for (int j = 0; j < 4; j++) acc[i][j] += av[i] * bv[j];
        }
        __syncthreads();
    }
    #pragma unroll
    for (int i = 0; i < 4; i++) {
        int row = tr * 4 + i;
        #pragma unroll
        for (int j = 0; j < 4; j++) {
            int col = n0 + tc * 4 + j;
            Cos[(size_t)b * LQ * LD + (size_t)row * LD + col] = acc[i][j];
        }
    }
}

// ---------------- kernel pooling: one wave per (b, qi); 21 RBF kernels ----------------
__global__ __launch_bounds__(256) void pool_kernel(const float* __restrict__ Cos, const float* __restrict__ mask_q,
                                                   const float* __restrict__ mask_d, const float* __restrict__ nn_scaler,
                                                   float* __restrict__ lp) {
    int wid = (blockIdx.x * 256 + threadIdx.x) >> 6;
    int lane = threadIdx.x & 63;
    int b = wid >> 6, qi = wid & 63;
    const float* crow = Cos + ((size_t)b * LQ + qi) * LD;
    const float* md = mask_d + b * LD;
    float acc[NK];
    #pragma unroll
    for (int k = 0; k < NK; k++) acc[k] = 0.f;
    #pragma unroll
    for (int r = 0; r < LD / 64; r++) {
        int dj = r * 64 + lane;
        float m = md[dj];
        if (m != 0.f) {
            float cv = crow[dj];
            #pragma unroll
            for (int k = 0; k < NK; k++) {
                float mu = (k == 0) ? 1.0f : (0.95f - 0.1f * (k - 1));
                float neg_inv = (k == 0) ? -500000.0f : -50.0f;
                float d = cv - mu;
                acc[k] += expf(d * d * neg_inv);
            }
        }
    }
    float mq = mask_q[b * LQ + qi];
    float ns = nn_scaler[0];
    #pragma unroll
    for (int k = 0; k < NK; k++) {
        float s = wave_sum(acc[k]);
        if (lane == 0) lp[((size_t)b * LQ + qi) * NK + k] = log2f(fmaxf(s, 1e-10f)) * ns * mq;
    }
}

// ---------------- final: out[b] = sum_k dense_w[k] * sum_qi lp[b,qi,k] ----------------
__global__ void final_kernel(const float* __restrict__ lp, const float* __restrict__ dense_w,
                             float* __restrict__ out) {
    int b = blockIdx.x;
    int t = threadIdx.x;  // 64 threads
    float s = 0.f;
    if (t < NK) {
        for (int qi = 0; qi < LQ; qi++) s += lp[((size_t)b * LQ + qi) * NK + t];
        s *= dense_w[t];
    }
    s = wave_sum(s);
    if (t == 0) out[b] = s;
}

extern "C" void kernel_launch(void* const* d_in, const int* in_sizes, int n_in,
                              void* d_out, int out_size, void* d_ws, size_t ws_size,
                              hipStream_t stream) {
    (void)in_sizes; (void)n_in; (void)out_size; (void)ws_size;
    const float* q_embed  = (const float*)d_in[0];
    const float* d_embed  = (const float*)d_in[1];
    const float* mask_q   = (const float*)d_in[2];
    const float* mask_d   = (const float*)d_in[3];
    const float* mixer    = (const float*)d_in[4];
    const float* nn_scaler= (const float*)d_in[5];
    const float* ff_w1    = (const float*)d_in[6];
    const float* ff_b1    = (const float*)d_in[7];
    const float* ff_w2    = (const float*)d_in[8];
    const float* ff_b2    = (const float*)d_in[9];
    const float* ln1_g    = (const float*)d_in[10];
    const float* ln1_b    = (const float*)d_in[11];
    const float* att_w    = (const float*)d_in[12];
    const float* att_b    = (const float*)d_in[13];
    const float* out_w    = (const float*)d_in[14];
    const float* out_b    = (const float*)d_in[15];
    const float* ln2_g    = (const float*)d_in[16];
    const float* ln2_b    = (const float*)d_in[17];
    const float* dense_w  = (const float*)d_in[18];
    float* out = (float*)d_out;

    // ---------------- workspace layout ----------------
    // fp32: x, xc, t2 (aliases: cb, qdn), hb (alias: cos), mall, lp
    // bf16: xabf (FF1-A for both layers), t1bf, hbbf, o32bf, transposed weights
    float* ws  = (float*)d_ws;
    float* x   = ws;                             // MALL*EMB
    float* xc  = x  + (size_t)MALL * EMB;
    float* t2  = xc + (size_t)MALL * EMB;        // also cb (ATT out) and qdn
    float* hb  = t2 + (size_t)MALL * EMB;        // also cos matrix
    float* mall = hb + (size_t)MALL * EMB;       // MALL
    float* lp  = mall + MALL;                    // 32*64*21 = 43008
    __hip_bfloat16* xabf  = (__hip_bfloat16*)(lp + 43008);
    __hip_bfloat16* t1bf  = xabf + (size_t)MALL * EMB;    // MALL*FFH
    __hip_bfloat16* hbbf  = t1bf + (size_t)MALL * FFH;    // MALL*EMB
    __hip_bfloat16* o32bf = hbbf + (size_t)MALL * EMB;    // MALL*ATTD
    __hip_bfloat16* w1t   = o32bf + (size_t)MALL * ATTD;  // 2*100*300
    __hip_bfloat16* w2t   = w1t + 2 * FFH * EMB;          // 2*300*100
    __hip_bfloat16* awt   = w2t + 2 * EMB * FFH;          // 2*96*300
    __hip_bfloat16* owt   = awt + 2 * 96 * EMB;           // 2*300*32

    // 0. weight convert + transpose (bf16)
    convert_wt<<<(2 * EMB * FFH + 255) / 256, 256, 0, stream>>>(ff_w1, w1t, 2, EMB, FFH);
    convert_wt<<<(2 * FFH * EMB + 255) / 256, 256, 0, stream>>>(ff_w2, w2t, 2, FFH, EMB);
    convert_wt<<<(2 * EMB * 96 + 255) / 256, 256, 0, stream>>>(att_w, awt, 2, EMB, 96);
    convert_wt<<<(2 * ATTD * EMB + 255) / 256, 256, 0, stream>>>(out_w, owt, 2, ATTD, EMB);

    // 1. masked inputs (fp32 + bf16) + mask concat
    maskmul_kernel<<<(MQ * EMB + 255) / 256, 256, 0, stream>>>(q_embed, mask_q, x, xabf, MQ * EMB);
    maskmul_kernel<<<(MD * EMB + 255) / 256, 256, 0, stream>>>(d_embed, mask_d,
        x + (size_t)MQ * EMB, xabf + (size_t)MQ * EMB, MD * EMB);
    maskcat_kernel<<<(MALL + 255) / 256, 256, 0, stream>>>(mask_q, mask_d, mall);

    // 2. merged encoder (MFMA GEMMs; attention splits by segment)
    const float* xcur = x;
    for (int l = 0; l < 2; l++) {
        // FF1: relu(x @ w1 + b1) -> t1 (bf16 only)
        gemm_mfma<true, false, true><<<dim3(2, MALL / 64), 256, 0, stream>>>(
            xabf, w1t + (size_t)l * FFH * EMB, ff_b1 + l * FFH, nullptr,
            nullptr, t1bf, MALL, FFH, EMB);
        // FF2: t1 @ w2 + b2 + x -> t2 (fp32)
        gemm_mfma<false, true, false><<<dim3(5, MALL / 64), 256, 0, stream>>>(
            t1bf, w2t + (size_t)l * EMB * FFH, ff_b2 + l * EMB, xcur,
            t2, nullptr, MALL, EMB, FFH);
        // LN1 -> hb fp32 + hbbf
        ln_kernel<true><<<MALL / 4, 256, 0, stream>>>(t2, ln1_g + l * EMB, ln1_b + l * EMB,
                                                      hb, hbbf, MALL);
        // ATT: hb @ att_w + att_b -> cb (t2 region, fp32)
        gemm_mfma<false, false, false><<<dim3(2, MALL / 64), 256, 0, stream>>>(
            hbbf, awt + (size_t)l * 96 * EMB, att_b + l * 96, nullptr,
            t2, nullptr, MALL, 96, EMB);
        // attention -> o32 (bf16)
        attn_fused<LQ, 64, 8><<<BATCH * NH, 512, 0, stream>>>(t2, mask_q, o32bf);
        attn_fused<LD, 128, 4><<<BATCH * NH * (LD / 128), 512, 0, stream>>>(
            t2 + (size_t)MQ * 96, mask_d, o32bf + (size_t)MQ * ATTD);
        // OUT: o32 @ out_w + out_b + hb -> t2 (fp32)
        gemm_mfma<false, true, false><<<dim3(5, MALL / 64), 256, 0, stream>>>(
            o32bf, owt + (size_t)l * EMB * ATTD, out_b + l * EMB, hb,
            t2, nullptr, MALL, EMB, ATTD);
        // LN2 -> xc fp32 (+ xabf bf16 for next layer's FF1)
        if (l == 0)
            ln_kernel<true><<<MALL / 4, 256, 0, stream>>>(t2, ln2_g, ln2_b, xc, xabf, MALL);
        else
            ln_kernel<false><<<MALL / 4, 256, 0, stream>>>(t2, ln2_g + EMB, ln2_b + EMB,
                                                           xc, nullptr, MALL);
        xcur = xc;
    }

    // 3. mix + normalize (merged) -> qdn (t2 region)
    mixnorm_kernel<<<MALL / 4, 256, 0, stream>>>(x, xc, mall, mixer, t2);

    // 4. cosine matrix (q segment vs d segment) -> cos (hb region)
    gemm_nt_cos<<<dim3(LD / 64, BATCH), 256, 0, stream>>>(t2, t2 + (size_t)MQ * EMB, hb);

    // 5. kernel pooling
    pool_kernel<<<(BATCH * LQ) / 4, 256, 0, stream>>>(hb, mask_q, mask_d, nn_scaler, lp);

    // 6. final projection
    final_kernel<<<BATCH, 64, 0, stream>>>(lp, dense_w, out);
}

// Round 8
// 297.780 us; speedup vs baseline: 1.7056x; 1.1012x over previous
//
#include <hip/hip_runtime.h>
#include <hip/hip_bf16.h>

// Problem constants
#define BATCH 32
#define LQ 64
#define LD 512
#define EMB 300
#define FFH 100
#define ATTD 32
#define NH 8
#define NK 21
#define MQ (BATCH * LQ)          // 2048 query tokens
#define MD (BATCH * LD)          // 16384 doc tokens
#define MALL (MQ + MD)           // 18432 merged tokens

typedef __attribute__((ext_vector_type(8))) short bf16x8;
typedef __attribute__((ext_vector_type(4))) float f32x4;

__device__ __forceinline__ float wave_sum(float v) {
    #pragma unroll
    for (int off = 32; off > 0; off >>= 1) v += __shfl_xor(v, off);
    return v;
}

// ---------------- elementwise: x = emb * mask(token), fp32 + bf16 copies ----------------
__global__ void maskmul_kernel(const float* __restrict__ emb, const float* __restrict__ mask,
                               float* __restrict__ out, __hip_bfloat16* __restrict__ outb, int n) {
    int i = blockIdx.x * blockDim.x + threadIdx.x;
    if (i < n) {
        float v = emb[i] * mask[i / EMB];
        out[i] = v;
        outb[i] = __float2bfloat16(v);
    }
}

// ---------------- mask concat: [mask_q | mask_d] -> maskall[18432] ----------------
__global__ void maskcat_kernel(const float* __restrict__ mq, const float* __restrict__ md,
                               float* __restrict__ out) {
    int i = blockIdx.x * blockDim.x + threadIdx.x;
    if (i < MALL) out[i] = (i < MQ) ? mq[i] : md[i - MQ];
}

// ---------------- weight convert + transpose: w[L][K][N] fp32 -> wt[L][N][K] bf16 ----------
__global__ void convert_wt(const float* __restrict__ w, __hip_bfloat16* __restrict__ wt,
                           int L, int K, int N) {
    int i = blockIdx.x * blockDim.x + threadIdx.x;
    int tot = L * K * N;
    if (i >= tot) return;
    int l = i / (K * N);
    int r = i % (K * N);
    int k = r / N, n = r % N;
    wt[(size_t)l * N * K + (size_t)n * K + k] = __float2bfloat16(w[i]);
}

// ---------------- shared staging helper: 8 bf16 of one row ----------------
__device__ __forceinline__ void stage_row8(const __hip_bfloat16* __restrict__ src, bool rowvalid,
                                           int K, int gk, __hip_bfloat16* dst) {
    if (rowvalid && gk + 8 <= K) {
        const uint2* p = (const uint2*)(src + gk);   // 8B-aligned (K even, gk%8==0)
        uint2 a = p[0], b = p[1];
        *(uint2*)dst = a;
        *(uint2*)(dst + 4) = b;
    } else {
        #pragma unroll
        for (int j = 0; j < 8; j++)
            dst[j] = (rowvalid && gk + j < K) ? src[gk + j] : __float2bfloat16(0.f);
    }
}

// ---------------- MFMA bf16 GEMM: C[M,N] = A[M,K] @ Bt[N,K]^T + bias (+relu/+res) --------
// 64x64 tile, 4 waves (2x2), each wave 32x32 via 2x2 mfma_f32_16x16x32_bf16 fragments.
// LDS [64][40] bf16 padded (frag reads 2-way conflict = free).
// D layout (m89-verified): col = lane&15, row = (lane>>4)*4 + reg.
template <bool RELU, bool HAS_RES, bool BF16OUT>
__global__ __launch_bounds__(256) void gemm_mfma(const __hip_bfloat16* __restrict__ A,
                                                 const __hip_bfloat16* __restrict__ Bt,
                                                 const float* __restrict__ bias,
                                                 const float* __restrict__ Rres,
                                                 float* __restrict__ C,
                                                 __hip_bfloat16* __restrict__ Cb,
                                                 int M, int N, int K) {
    __shared__ __align__(16) __hip_bfloat16 As[64][40];
    __shared__ __align__(16) __hip_bfloat16 Bs[64][40];
    const int tid = threadIdx.x;
    const int m0 = blockIdx.y * 64, n0 = blockIdx.x * 64;
    const int lane = tid & 63;
    const int wv = tid >> 6;
    const int wm = wv >> 1, wn = wv & 1;
    const int l15 = lane & 15, lg = lane >> 4;
    const int srow = tid >> 2, sk8 = (tid & 3) * 8;
    f32x4 acc[2][2] = {};
    const int NS = (K + 31) >> 5;
    const __hip_bfloat16* arow = A + (size_t)(m0 + srow) * K;
    const bool bvalid = (n0 + srow) < N;
    const __hip_bfloat16* brow = Bt + (size_t)(n0 + srow) * K;

    for (int s = 0; s < NS; s++) {
        const int gk = (s << 5) + sk8;
        if (s) __syncthreads();
        stage_row8(arow, true, K, gk, &As[srow][sk8]);
        stage_row8(brow, bvalid, K, gk, &Bs[srow][sk8]);
        __syncthreads();
        bf16x8 af0 = *(const bf16x8*)&As[wm * 32 + l15][lg * 8];
        bf16x8 af1 = *(const bf16x8*)&As[wm * 32 + 16 + l15][lg * 8];
        bf16x8 bf0 = *(const bf16x8*)&Bs[wn * 32 + l15][lg * 8];
        bf16x8 bf1 = *(const bf16x8*)&Bs[wn * 32 + 16 + l15][lg * 8];
        acc[0][0] = __builtin_amdgcn_mfma_f32_16x16x32_bf16(af0, bf0, acc[0][0], 0, 0, 0);
        acc[0][1] = __builtin_amdgcn_mfma_f32_16x16x32_bf16(af0, bf1, acc[0][1], 0, 0, 0);
        acc[1][0] = __builtin_amdgcn_mfma_f32_16x16x32_bf16(af1, bf0, acc[1][0], 0, 0, 0);
        acc[1][1] = __builtin_amdgcn_mfma_f32_16x16x32_bf16(af1, bf1, acc[1][1], 0, 0, 0);
    }

    #pragma unroll
    for (int fc = 0; fc < 2; fc++) {
        int col = n0 + wn * 32 + fc * 16 + l15;
        if (col >= N) continue;
        float bs = bias[col];
        #pragma unroll
        for (int fr = 0; fr < 2; fr++) {
            int rbase = m0 + wm * 32 + fr * 16 + lg * 4;
            #pragma unroll
            for (int r = 0; r < 4; r++) {
                int row = rbase + r;
                float v = acc[fr][fc][r] + bs;
                if (RELU) v = fmaxf(v, 0.f);
                size_t idx = (size_t)row * N + col;
                if (HAS_RES) v += Rres[idx];
                if (BF16OUT) Cb[idx] = __float2bfloat16(v);
                else C[idx] = v;
            }
        }
    }
}

// ---------------- batched MFMA cos GEMM: Cos[b] = Qn[b] (64xK) @ Dn[b] (512xK)^T -------
// grid (LD/64, BATCH). Same tile/fragment structure as gemm_mfma; no bias/relu/res.
__global__ __launch_bounds__(256) void cos_mfma(const __hip_bfloat16* __restrict__ Qn,
                                                const __hip_bfloat16* __restrict__ Dn,
                                                float* __restrict__ Cos) {
    __shared__ __align__(16) __hip_bfloat16 As[64][40];
    __shared__ __align__(16) __hip_bfloat16 Bs[64][40];
    const int b = blockIdx.y;
    const int n0 = blockIdx.x * 64;
    const int tid = threadIdx.x;
    const int lane = tid & 63;
    const int wv = tid >> 6;
    const int wm = wv >> 1, wn = wv & 1;
    const int l15 = lane & 15, lg = lane >> 4;
    const int srow = tid >> 2, sk8 = (tid & 3) * 8;
    f32x4 acc[2][2] = {};
    const int NS = (EMB + 31) >> 5;   // 10
    const __hip_bfloat16* arow = Qn + ((size_t)b * LQ + srow) * EMB;
    const __hip_bfloat16* brow = Dn + ((size_t)b * LD + n0 + srow) * EMB;

    for (int s = 0; s < NS; s++) {
        const int gk = (s << 5) + sk8;
        if (s) __syncthreads();
        stage_row8(arow, true, EMB, gk, &As[srow][sk8]);
        stage_row8(brow, true, EMB, gk, &Bs[srow][sk8]);
        __syncthreads();
        bf16x8 af0 = *(const bf16x8*)&As[wm * 32 + l15][lg * 8];
        bf16x8 af1 = *(const bf16x8*)&As[wm * 32 + 16 + l15][lg * 8];
        bf16x8 bf0 = *(const bf16x8*)&Bs[wn * 32 + l15][lg * 8];
        bf16x8 bf1 = *(const bf16x8*)&Bs[wn * 32 + 16 + l15][lg * 8];
        acc[0][0] = __builtin_amdgcn_mfma_f32_16x16x32_bf16(af0, bf0, acc[0][0], 0, 0, 0);
        acc[0][1] = __builtin_amdgcn_mfma_f32_16x16x32_bf16(af0, bf1, acc[0][1], 0, 0, 0);
        acc[1][0] = __builtin_amdgcn_mfma_f32_16x16x32_bf16(af1, bf0, acc[1][0], 0, 0, 0);
        acc[1][1] = __builtin_amdgcn_mfma_f32_16x16x32_bf16(af1, bf1, acc[1][1], 0, 0, 0);
    }

    float* cb = Cos + (size_t)b * LQ * LD;
    #pragma unroll
    for (int fc = 0; fc < 2; fc++) {
        int col = n0 + wn * 32 + fc * 16 + l15;
        #pragma unroll
        for (int fr = 0; fr < 2; fr++) {
            int rbase = wm * 32 + fr * 16 + lg * 4;
            #pragma unroll
            for (int r = 0; r < 4; r++) {
                cb[(size_t)(rbase + r) * LD + col] = acc[fr][fc][r];
            }
        }
    }
}

// ---------------- LayerNorm (ddof=1, eps added to std); optional bf16 copy ----------------
template <bool EMITB>
__global__ __launch_bounds__(256) void ln_kernel(const float* __restrict__ X, const float* __restrict__ g,
                                                 const float* __restrict__ bta, float* __restrict__ Y,
                                                 __hip_bfloat16* __restrict__ Yb, int M) {
    int wid = (blockIdx.x * 256 + threadIdx.x) >> 6;
    int lane = threadIdx.x & 63;
    if (wid >= M) return;
    const float* x = X + (size_t)wid * EMB;
    float v[5];
    float s = 0.f;
    #pragma unroll
    for (int r = 0; r < 5; r++) {
        int idx = lane + r * 64;
        float val = (idx < EMB) ? x[idx] : 0.f;
        v[r] = val;
        s += val;
    }
    s = wave_sum(s);
    float mean = s * (1.f / EMB);
    float s2 = 0.f;
    #pragma unroll
    for (int r = 0; r < 5; r++) {
        int idx = lane + r * 64;
        if (idx < EMB) { float d = v[r] - mean; s2 += d * d; }
    }
    s2 = wave_sum(s2);
    float stdv = sqrtf(s2 * (1.f / (EMB - 1)));
    float inv = 1.f / (stdv + 1e-6f);
    float* y = Y + (size_t)wid * EMB;
    __hip_bfloat16* yb = EMITB ? (Yb + (size_t)wid * EMB) : nullptr;
    #pragma unroll
    for (int r = 0; r < 5; r++) {
        int idx = lane + r * 64;
        if (idx < EMB) {
            float val = g[idx] * (v[r] - mean) * inv + bta[idx];
            y[idx] = val;
            if (EMITB) yb[idx] = __float2bfloat16(val);
        }
    }
}

// ---------------- attention: single-pass (no max), premasked K/V in LDS, k-split ---------
// c layout: [tokens, 96]  (q | k | v, each 32 = 8 heads * 4). Output bf16.
template <int T, int RPB, int KS>
__global__ __launch_bounds__(512) void attn_fused(const float* __restrict__ c,
                                                  const float* __restrict__ mask,
                                                  __hip_bfloat16* __restrict__ o32) {
    constexpr int BLK = RPB * KS;
    constexpr int NRB = T / RPB;
    __shared__ float4 Ks[T];
    __shared__ float4 Vs[T];
    __shared__ float part[RPB * 5 * (KS - 1)];
    __shared__ float nmask_s;
    const int bh = blockIdx.x / NRB;
    const int rb = blockIdx.x % NRB;
    const int b = bh / NH, h = bh % NH;
    const int tid = threadIdx.x;
    const float* base = c + (size_t)b * T * 96;

    if (tid == 0) nmask_s = 0.f;
    __syncthreads();
    float lnm = 0.f;
    for (int j = tid; j < T; j += BLK) {
        float m = mask[b * T + j];
        float4 kv = *(const float4*)(base + (size_t)j * 96 + ATTD + h * 4);
        float4 vv = *(const float4*)(base + (size_t)j * 96 + 2 * ATTD + h * 4);
        kv.x *= m; kv.y *= m; kv.z *= m; kv.w *= m;
        vv.x *= m; vv.y *= m; vv.z *= m; vv.w *= m;
        Ks[j] = kv;
        Vs[j] = vv;
        lnm += 1.f - m;
    }
    lnm = wave_sum(lnm);
    if ((tid & 63) == 0 && lnm != 0.f) atomicAdd(&nmask_s, lnm);
    __syncthreads();

    const int r = rb * RPB + (tid % RPB);
    const int ks = tid / RPB;
    const float inv_scale = 0.16439898730535729f;  // 1/sqrt(37)
    float4 qv = *(const float4*)(base + (size_t)r * 96 + h * 4);
    qv.x *= inv_scale; qv.y *= inv_scale; qv.z *= inv_scale; qv.w *= inv_scale;

    float Sall = 0.f, ox = 0.f, oy = 0.f, oz = 0.f, ow = 0.f;
    constexpr int KC = T / KS;
    const int k0 = ks * KC;
    #pragma unroll 4
    for (int k = k0; k < k0 + KC; k++) {
        float4 kv = Ks[k];
        float4 vv = Vs[k];
        float s = fmaf(qv.x, kv.x, fmaf(qv.y, kv.y, fmaf(qv.z, kv.z, qv.w * kv.w)));
        float e = __expf(s);
        Sall += e;
        ox = fmaf(e, vv.x, ox);
        oy = fmaf(e, vv.y, oy);
        oz = fmaf(e, vv.z, oz);
        ow = fmaf(e, vv.w, ow);
    }
    if (ks > 0) {
        float* p = &part[((ks - 1) * RPB + (tid % RPB)) * 5];
        p[0] = Sall; p[1] = ox; p[2] = oy; p[3] = oz; p[4] = ow;
    }
    __syncthreads();
    if (ks == 0) {
        #pragma unroll
        for (int s2 = 0; s2 < KS - 1; s2++) {
            const float* p = &part[(s2 * RPB + r - rb * RPB) * 5];
            Sall += p[0]; ox += p[1]; oy += p[2]; oz += p[3]; ow += p[4];
        }
        float Sm = Sall - nmask_s;
        float inv = 1.f / (Sm + 1e-13f * Sall);
        __hip_bfloat16* op = o32 + (size_t)(b * T + r) * ATTD + h * 4;
        op[0] = __float2bfloat16(ox * inv);
        op[1] = __float2bfloat16(oy * inv);
        op[2] = __float2bfloat16(oz * inv);
        op[3] = __float2bfloat16(ow * inv);
    }
}

// ---------------- mix + L2 normalize: one wave per token; bf16 output ----------------
__global__ __launch_bounds__(256) void mixnorm_kernel(const float* __restrict__ x, const float* __restrict__ xc,
                                                      const float* __restrict__ mask, const float* __restrict__ mixer,
                                                      __hip_bfloat16* __restrict__ out) {
    int wid = (blockIdx.x * 256 + threadIdx.x) >> 6;
    int lane = threadIdx.x & 63;
    float mixv = mixer[0];
    float mval = mask[wid];
    const float* xr = x + (size_t)wid * EMB;
    const float* xcr = xc + (size_t)wid * EMB;
    float v[5];
    float s2 = 0.f;
    #pragma unroll
    for (int r = 0; r < 5; r++) {
        int idx = lane + r * 64;
        float val = 0.f;
        if (idx < EMB) val = (mixv * xr[idx] + (1.f - mixv) * xcr[idx]) * mval;
        v[r] = val;
        s2 += val * val;
    }
    s2 = wave_sum(s2);
    float inv = 1.f / (sqrtf(s2) + 1e-13f);
    __hip_bfloat16* o = out + (size_t)wid * EMB;
    #pragma unroll
    for (int r = 0; r < 5; r++) {
        int idx = lane + r * 64;
        if (idx < EMB) o[idx] = __float2bfloat16(v[r] * inv);
    }
}

// ---------------- kernel pooling: one wave per (b, qi); 21 RBF kernels ----------------
__global__ __launch_bounds__(256) void pool_kernel(const float* __restrict__ Cos, const float* __restrict__ mask_q,
                                                   const float* __restrict__ mask_d, const float* __restrict__ nn_scaler,
                                                   float* __restrict__ lp) {
    int wid = (blockIdx.x * 256 + threadIdx.x) >> 6;
    int lane = threadIdx.x & 63;
    int b = wid >> 6, qi = wid & 63;
    const float* crow = Cos + ((size_t)b * LQ + qi) * LD;
    const float* md = mask_d + b * LD;
    float acc[NK];
    #pragma unroll
    for (int k = 0; k < NK; k++) acc[k] = 0.f;
    #pragma unroll
    for (int r = 0; r < LD / 64; r++) {
        int dj = r * 64 + lane;
        float m = md[dj];
        if (m != 0.f) {
            float cv = crow[dj];
            #pragma unroll
            for (int k = 0; k < NK; k++) {
                float mu = (k == 0) ? 1.0f : (0.95f - 0.1f * (k - 1));
                float neg_inv = (k == 0) ? -500000.0f : -50.0f;
                float d = cv - mu;
                acc[k] += expf(d * d * neg_inv);
            }
        }
    }
    float mq = mask_q[b * LQ + qi];
    float ns = nn_scaler[0];
    #pragma unroll
    for (int k = 0; k < NK; k++) {
        float s = wave_sum(acc[k]);
        if (lane == 0) lp[((size_t)b * LQ + qi) * NK + k] = log2f(fmaxf(s, 1e-10f)) * ns * mq;
    }
}

// ---------------- final: out[b] = sum_k dense_w[k] * sum_qi lp[b,qi,k] ----------------
__global__ void final_kernel(const float* __restrict__ lp, const float* __restrict__ dense_w,
                             float* __restrict__ out) {
    int b = blockIdx.x;
    int t = threadIdx.x;  // 64 threads
    float s = 0.f;
    if (t < NK) {
        for (int qi = 0; qi < LQ; qi++) s += lp[((size_t)b * LQ + qi) * NK + t];
        s *= dense_w[t];
    }
    s = wave_sum(s);
    if (t == 0) out[b] = s;
}

extern "C" void kernel_launch(void* const* d_in, const int* in_sizes, int n_in,
                              void* d_out, int out_size, void* d_ws, size_t ws_size,
                              hipStream_t stream) {
    (void)in_sizes; (void)n_in; (void)out_size; (void)ws_size;
    const float* q_embed  = (const float*)d_in[0];
    const float* d_embed  = (const float*)d_in[1];
    const float* mask_q   = (const float*)d_in[2];
    const float* mask_d   = (const float*)d_in[3];
    const float* mixer    = (const float*)d_in[4];
    const float* nn_scaler= (const float*)d_in[5];
    const float* ff_w1    = (const float*)d_in[6];
    const float* ff_b1    = (const float*)d_in[7];
    const float* ff_w2    = (const float*)d_in[8];
    const float* ff_b2    = (const float*)d_in[9];
    const float* ln1_g    = (const float*)d_in[10];
    const float* ln1_b    = (const float*)d_in[11];
    const float* att_w    = (const float*)d_in[12];
    const float* att_b    = (const float*)d_in[13];
    const float* out_w    = (const float*)d_in[14];
    const float* out_b    = (const float*)d_in[15];
    const float* ln2_g    = (const float*)d_in[16];
    const float* ln2_b    = (const float*)d_in[17];
    const float* dense_w  = (const float*)d_in[18];
    float* out = (float*)d_out;

    // ---------------- workspace layout ----------------
    float* ws  = (float*)d_ws;
    float* x   = ws;                             // MALL*EMB
    float* xc  = x  + (size_t)MALL * EMB;
    float* t2  = xc + (size_t)MALL * EMB;        // also cb (ATT out)
    float* hb  = t2 + (size_t)MALL * EMB;        // also cos matrix
    float* mall = hb + (size_t)MALL * EMB;       // MALL
    float* lp  = mall + MALL;                    // 32*64*21 = 43008
    __hip_bfloat16* xabf  = (__hip_bfloat16*)(lp + 43008);  // MALL*EMB; post-encoder: qdn bf16
    __hip_bfloat16* t1bf  = xabf + (size_t)MALL * EMB;    // MALL*FFH
    __hip_bfloat16* hbbf  = t1bf + (size_t)MALL * FFH;    // MALL*EMB
    __hip_bfloat16* o32bf = hbbf + (size_t)MALL * EMB;    // MALL*ATTD
    __hip_bfloat16* w1t   = o32bf + (size_t)MALL * ATTD;  // 2*100*300
    __hip_bfloat16* w2t   = w1t + 2 * FFH * EMB;          // 2*300*100
    __hip_bfloat16* awt   = w2t + 2 * EMB * FFH;          // 2*96*300
    __hip_bfloat16* owt   = awt + 2 * 96 * EMB;           // 2*300*32

    // 0. weight convert + transpose (bf16)
    convert_wt<<<(2 * EMB * FFH + 255) / 256, 256, 0, stream>>>(ff_w1, w1t, 2, EMB, FFH);
    convert_wt<<<(2 * FFH * EMB + 255) / 256, 256, 0, stream>>>(ff_w2, w2t, 2, FFH, EMB);
    convert_wt<<<(2 * EMB * 96 + 255) / 256, 256, 0, stream>>>(att_w, awt, 2, EMB, 96);
    convert_wt<<<(2 * ATTD * EMB + 255) / 256, 256, 0, stream>>>(out_w, owt, 2, ATTD, EMB);

    // 1. masked inputs (fp32 + bf16) + mask concat
    maskmul_kernel<<<(MQ * EMB + 255) / 256, 256, 0, stream>>>(q_embed, mask_q, x, xabf, MQ * EMB);
    maskmul_kernel<<<(MD * EMB + 255) / 256, 256, 0, stream>>>(d_embed, mask_d,
        x + (size_t)MQ * EMB, xabf + (size_t)MQ * EMB, MD * EMB);
    maskcat_kernel<<<(MALL + 255) / 256, 256, 0, stream>>>(mask_q, mask_d, mall);

    // 2. merged encoder (MFMA GEMMs; attention splits by segment)
    const float* xcur = x;
    for (int l = 0; l < 2; l++) {
        // FF1: relu(x @ w1 + b1) -> t1 (bf16 only)
        gemm_mfma<true, false, true><<<dim3(2, MALL / 64), 256, 0, stream>>>(
            xabf, w1t + (size_t)l * FFH * EMB, ff_b1 + l * FFH, nullptr,
            nullptr, t1bf, MALL, FFH, EMB);
        // FF2: t1 @ w2 + b2 + x -> t2 (fp32)
        gemm_mfma<false, true, false><<<dim3(5, MALL / 64), 256, 0, stream>>>(
            t1bf, w2t + (size_t)l * EMB * FFH, ff_b2 + l * EMB, xcur,
            t2, nullptr, MALL, EMB, FFH);
        // LN1 -> hb fp32 + hbbf
        ln_kernel<true><<<MALL / 4, 256, 0, stream>>>(t2, ln1_g + l * EMB, ln1_b + l * EMB,
                                                      hb, hbbf, MALL);
        // ATT: hb @ att_w + att_b -> cb (t2 region, fp32)
        gemm_mfma<false, false, false><<<dim3(2, MALL / 64), 256, 0, stream>>>(
            hbbf, awt + (size_t)l * 96 * EMB, att_b + l * 96, nullptr,
            t2, nullptr, MALL, 96, EMB);
        // attention -> o32 (bf16)
        attn_fused<LQ, 64, 8><<<BATCH * NH, 512, 0, stream>>>(t2, mask_q, o32bf);
        attn_fused<LD, 128, 4><<<BATCH * NH * (LD / 128), 512, 0, stream>>>(
            t2 + (size_t)MQ * 96, mask_d, o32bf + (size_t)MQ * ATTD);
        // OUT: o32 @ out_w + out_b + hb -> t2 (fp32)
        gemm_mfma<false, true, false><<<dim3(5, MALL / 64), 256, 0, stream>>>(
            o32bf, owt + (size_t)l * EMB * ATTD, out_b + l * EMB, hb,
            t2, nullptr, MALL, EMB, ATTD);
        // LN2 -> xc fp32 (+ xabf bf16 for next layer's FF1)
        if (l == 0)
            ln_kernel<true><<<MALL / 4, 256, 0, stream>>>(t2, ln2_g, ln2_b, xc, xabf, MALL);
        else
            ln_kernel<false><<<MALL / 4, 256, 0, stream>>>(t2, ln2_g + EMB, ln2_b + EMB,
                                                           xc, nullptr, MALL);
        xcur = xc;
    }

    // 3. mix + normalize (merged) -> qdn bf16 (xabf region, free after encoder)
    mixnorm_kernel<<<MALL / 4, 256, 0, stream>>>(x, xc, mall, mixer, xabf);

    // 4. cosine matrix via MFMA (q segment vs d segment) -> cos (hb region)
    cos_mfma<<<dim3(LD / 64, BATCH), 256, 0, stream>>>(xabf, xabf + (size_t)MQ * EMB, hb);

    // 5. kernel pooling
    pool_kernel<<<(BATCH * LQ) / 4, 256, 0, stream>>>(hb, mask_q, mask_d, nn_scaler, lp);

    // 6. final projection
    final_kernel<<<BATCH, 64, 0, stream>>>(lp, dense_w, out);
}

// Round 9
// 242.802 us; speedup vs baseline: 2.0918x; 1.2264x over previous
//
#include <hip/hip_runtime.h>
#include <hip/hip_bf16.h>

// Problem constants
#define BATCH 32
#define LQ 64
#define LD 512
#define EMB 300
#define FFH 100
#define ATTD 32
#define NH 8
#define NK 21
#define MQ (BATCH * LQ)          // 2048 query tokens
#define MD (BATCH * LD)          // 16384 doc tokens
#define MALL (MQ + MD)           // 18432 merged tokens

typedef __attribute__((ext_vector_type(8))) short bf16x8;
typedef __attribute__((ext_vector_type(4))) float f32x4;

__device__ __forceinline__ float wave_sum(float v) {
    #pragma unroll
    for (int off = 32; off > 0; off >>= 1) v += __shfl_xor(v, off);
    return v;
}

__device__ __forceinline__ float bf2f(__hip_bfloat16 h) {
    return __bfloat162float(h);
}

// 4 consecutive bf16 -> float4 (8B-aligned source)
__device__ __forceinline__ float4 bf4_to_f4(const __hip_bfloat16* p) {
    uint2 u = *(const uint2*)p;
    float4 f;
    f.x = __uint_as_float((u.x & 0xffffu) << 16);
    f.y = __uint_as_float(u.x & 0xffff0000u);
    f.z = __uint_as_float((u.y & 0xffffu) << 16);
    f.w = __uint_as_float(u.y & 0xffff0000u);
    return f;
}

// ---------------- fused input prep: xbf = bf16(emb*mask), mall = concat masks ------------
__global__ void maskmul_all(const float* __restrict__ q_embed, const float* __restrict__ d_embed,
                            const float* __restrict__ mask_q, const float* __restrict__ mask_d,
                            __hip_bfloat16* __restrict__ xbf, float* __restrict__ mall) {
    int i = blockIdx.x * blockDim.x + threadIdx.x;
    if (i >= MALL * EMB) return;
    int tok = i / EMB;
    float m, v;
    if (tok < MQ) {
        m = mask_q[tok];
        v = q_embed[i];
    } else {
        m = mask_d[tok - MQ];
        v = d_embed[i - MQ * EMB];
    }
    xbf[i] = __float2bfloat16(v * m);
    if (i % EMB == 0) mall[tok] = m;
}

// ---------------- all weights convert + transpose in one kernel ----------------
// w[L][K][N] fp32 -> wt[L][N][K] bf16 for 4 weight groups
__device__ __forceinline__ void conv_seg(const float* __restrict__ w, __hip_bfloat16* __restrict__ wt,
                                         int j, int K, int N) {
    int l = j / (K * N);
    int r = j % (K * N);
    int k = r / N, n = r % N;
    wt[(size_t)l * N * K + (size_t)n * K + k] = __float2bfloat16(w[j]);
}
__global__ void convert_all(const float* __restrict__ w1, const float* __restrict__ w2,
                            const float* __restrict__ aw, const float* __restrict__ ow,
                            __hip_bfloat16* __restrict__ w1t, __hip_bfloat16* __restrict__ w2t,
                            __hip_bfloat16* __restrict__ awt, __hip_bfloat16* __restrict__ owt) {
    int i = blockIdx.x * blockDim.x + threadIdx.x;
    const int S1 = 2 * EMB * FFH;        // 60000
    const int S2 = S1 + 2 * FFH * EMB;   // 120000
    const int S3 = S2 + 2 * EMB * 96;    // 177600
    const int S4 = S3 + 2 * ATTD * EMB;  // 196800
    if (i < S1)       conv_seg(w1, w1t, i, EMB, FFH);
    else if (i < S2)  conv_seg(w2, w2t, i - S1, FFH, EMB);
    else if (i < S3)  conv_seg(aw, awt, i - S2, EMB, 96);
    else if (i < S4)  conv_seg(ow, owt, i - S3, ATTD, EMB);
}

// ---------------- shared staging helper: 8 bf16 of one row ----------------
__device__ __forceinline__ void stage_row8(const __hip_bfloat16* __restrict__ src, bool rowvalid,
                                           int K, int gk, __hip_bfloat16* dst) {
    if (rowvalid && gk + 8 <= K) {
        const uint2* p = (const uint2*)(src + gk);
        uint2 a = p[0], b = p[1];
        *(uint2*)dst = a;
        *(uint2*)(dst + 4) = b;
    } else {
        #pragma unroll
        for (int j = 0; j < 8; j++)
            dst[j] = (rowvalid && gk + j < K) ? src[gk + j] : __float2bfloat16(0.f);
    }
}

// ---------------- MFMA bf16 GEMM: Cb[M,N] = A[M,K] @ Bt[N,K]^T + bias (+relu/+bf16 res) --
// 64x64 tile, 4 waves (2x2), each wave 32x32 via 2x2 mfma_f32_16x16x32_bf16 fragments.
// D layout (m89-verified): col = lane&15, row = (lane>>4)*4 + reg.
template <bool RELU, bool HAS_RES>
__global__ __launch_bounds__(256) void gemm_mfma(const __hip_bfloat16* __restrict__ A,
                                                 const __hip_bfloat16* __restrict__ Bt,
                                                 const float* __restrict__ bias,
                                                 const __hip_bfloat16* __restrict__ Rres,
                                                 __hip_bfloat16* __restrict__ Cb,
                                                 int M, int N, int K) {
    __shared__ __align__(16) __hip_bfloat16 As[64][40];
    __shared__ __align__(16) __hip_bfloat16 Bs[64][40];
    const int tid = threadIdx.x;
    const int m0 = blockIdx.y * 64, n0 = blockIdx.x * 64;
    const int lane = tid & 63;
    const int wv = tid >> 6;
    const int wm = wv >> 1, wn = wv & 1;
    const int l15 = lane & 15, lg = lane >> 4;
    const int srow = tid >> 2, sk8 = (tid & 3) * 8;
    f32x4 acc[2][2] = {};
    const int NS = (K + 31) >> 5;
    const __hip_bfloat16* arow = A + (size_t)(m0 + srow) * K;
    const bool bvalid = (n0 + srow) < N;
    const __hip_bfloat16* brow = Bt + (size_t)(n0 + srow) * K;

    for (int s = 0; s < NS; s++) {
        const int gk = (s << 5) + sk8;
        if (s) __syncthreads();
        stage_row8(arow, true, K, gk, &As[srow][sk8]);
        stage_row8(brow, bvalid, K, gk, &Bs[srow][sk8]);
        __syncthreads();
        bf16x8 af0 = *(const bf16x8*)&As[wm * 32 + l15][lg * 8];
        bf16x8 af1 = *(const bf16x8*)&As[wm * 32 + 16 + l15][lg * 8];
        bf16x8 bf0 = *(const bf16x8*)&Bs[wn * 32 + l15][lg * 8];
        bf16x8 bf1 = *(const bf16x8*)&Bs[wn * 32 + 16 + l15][lg * 8];
        acc[0][0] = __builtin_amdgcn_mfma_f32_16x16x32_bf16(af0, bf0, acc[0][0], 0, 0, 0);
        acc[0][1] = __builtin_amdgcn_mfma_f32_16x16x32_bf16(af0, bf1, acc[0][1], 0, 0, 0);
        acc[1][0] = __builtin_amdgcn_mfma_f32_16x16x32_bf16(af1, bf0, acc[1][0], 0, 0, 0);
        acc[1][1] = __builtin_amdgcn_mfma_f32_16x16x32_bf16(af1, bf1, acc[1][1], 0, 0, 0);
    }

    #pragma unroll
    for (int fc = 0; fc < 2; fc++) {
        int col = n0 + wn * 32 + fc * 16 + l15;
        if (col >= N) continue;
        float bs = bias[col];
        #pragma unroll
        for (int fr = 0; fr < 2; fr++) {
            int rbase = m0 + wm * 32 + fr * 16 + lg * 4;
            #pragma unroll
            for (int r = 0; r < 4; r++) {
                int row = rbase + r;
                float v = acc[fr][fc][r] + bs;
                if (RELU) v = fmaxf(v, 0.f);
                size_t idx = (size_t)row * N + col;
                if (HAS_RES) v += bf2f(Rres[idx]);
                Cb[idx] = __float2bfloat16(v);
            }
        }
    }
}

// ---------------- batched MFMA cos GEMM: Cos[b] = Qn[b] (64xK) @ Dn[b] (512xK)^T (fp32 out)
__global__ __launch_bounds__(256) void cos_mfma(const __hip_bfloat16* __restrict__ Qn,
                                                const __hip_bfloat16* __restrict__ Dn,
                                                float* __restrict__ Cos) {
    __shared__ __align__(16) __hip_bfloat16 As[64][40];
    __shared__ __align__(16) __hip_bfloat16 Bs[64][40];
    const int b = blockIdx.y;
    const int n0 = blockIdx.x * 64;
    const int tid = threadIdx.x;
    const int lane = tid & 63;
    const int wv = tid >> 6;
    const int wm = wv >> 1, wn = wv & 1;
    const int l15 = lane & 15, lg = lane >> 4;
    const int srow = tid >> 2, sk8 = (tid & 3) * 8;
    f32x4 acc[2][2] = {};
    const int NS = (EMB + 31) >> 5;   // 10
    const __hip_bfloat16* arow = Qn + ((size_t)b * LQ + srow) * EMB;
    const __hip_bfloat16* brow = Dn + ((size_t)b * LD + n0 + srow) * EMB;

    for (int s = 0; s < NS; s++) {
        const int gk = (s << 5) + sk8;
        if (s) __syncthreads();
        stage_row8(arow, true, EMB, gk, &As[srow][sk8]);
        stage_row8(brow, true, EMB, gk, &Bs[srow][sk8]);
        __syncthreads();
        bf16x8 af0 = *(const bf16x8*)&As[wm * 32 + l15][lg * 8];
        bf16x8 af1 = *(const bf16x8*)&As[wm * 32 + 16 + l15][lg * 8];
        bf16x8 bf0 = *(const bf16x8*)&Bs[wn * 32 + l15][lg * 8];
        bf16x8 bf1 = *(const bf16x8*)&Bs[wn * 32 + 16 + l15][lg * 8];
        acc[0][0] = __builtin_amdgcn_mfma_f32_16x16x32_bf16(af0, bf0, acc[0][0], 0, 0, 0);
        acc[0][1] = __builtin_amdgcn_mfma_f32_16x16x32_bf16(af0, bf1, acc[0][1], 0, 0, 0);
        acc[1][0] = __builtin_amdgcn_mfma_f32_16x16x32_bf16(af1, bf0, acc[1][0], 0, 0, 0);
        acc[1][1] = __builtin_amdgcn_mfma_f32_16x16x32_bf16(af1, bf1, acc[1][1], 0, 0, 0);
    }

    float* cb = Cos + (size_t)b * LQ * LD;
    #pragma unroll
    for (int fc = 0; fc < 2; fc++) {
        int col = n0 + wn * 32 + fc * 16 + l15;
        #pragma unroll
        for (int fr = 0; fr < 2; fr++) {
            int rbase = wm * 32 + fr * 16 + lg * 4;
            #pragma unroll
            for (int r = 0; r < 4; r++) {
                cb[(size_t)(rbase + r) * LD + col] = acc[fr][fc][r];
            }
        }
    }
}

// ---------------- LayerNorm bf16->bf16 (ddof=1, eps added to std, fp32 math) -------------
__global__ __launch_bounds__(256) void ln_bf(const __hip_bfloat16* __restrict__ X,
                                             const float* __restrict__ g,
                                             const float* __restrict__ bta,
                                             __hip_bfloat16* __restrict__ Y, int M) {
    int wid = (blockIdx.x * 256 + threadIdx.x) >> 6;
    int lane = threadIdx.x & 63;
    if (wid >= M) return;
    const __hip_bfloat16* x = X + (size_t)wid * EMB;
    float v[5];
    float s = 0.f;
    #pragma unroll
    for (int r = 0; r < 5; r++) {
        int idx = lane + r * 64;
        float val = (idx < EMB) ? bf2f(x[idx]) : 0.f;
        v[r] = val;
        s += val;
    }
    s = wave_sum(s);
    float mean = s * (1.f / EMB);
    float s2 = 0.f;
    #pragma unroll
    for (int r = 0; r < 5; r++) {
        int idx = lane + r * 64;
        if (idx < EMB) { float d = v[r] - mean; s2 += d * d; }
    }
    s2 = wave_sum(s2);
    float stdv = sqrtf(s2 * (1.f / (EMB - 1)));
    float inv = 1.f / (stdv + 1e-6f);
    __hip_bfloat16* y = Y + (size_t)wid * EMB;
    #pragma unroll
    for (int r = 0; r < 5; r++) {
        int idx = lane + r * 64;
        if (idx < EMB) y[idx] = __float2bfloat16(g[idx] * (v[r] - mean) * inv + bta[idx]);
    }
}

// ---------------- attention: bf16 input c[tokens][96], single-pass, premasked LDS --------
template <int T, int RPB, int KS>
__global__ __launch_bounds__(512) void attn_fused(const __hip_bfloat16* __restrict__ c,
                                                  const float* __restrict__ mask,
                                                  __hip_bfloat16* __restrict__ o32) {
    constexpr int BLK = RPB * KS;
    constexpr int NRB = T / RPB;
    __shared__ float4 Ks[T];
    __shared__ float4 Vs[T];
    __shared__ float part[RPB * 5 * (KS - 1)];
    __shared__ float nmask_s;
    const int bh = blockIdx.x / NRB;
    const int rb = blockIdx.x % NRB;
    const int b = bh / NH, h = bh % NH;
    const int tid = threadIdx.x;
    const __hip_bfloat16* base = c + (size_t)b * T * 96;

    if (tid == 0) nmask_s = 0.f;
    __syncthreads();
    float lnm = 0.f;
    for (int j = tid; j < T; j += BLK) {
        float m = mask[b * T + j];
        float4 kv = bf4_to_f4(base + (size_t)j * 96 + ATTD + h * 4);
        float4 vv = bf4_to_f4(base + (size_t)j * 96 + 2 * ATTD + h * 4);
        kv.x *= m; kv.y *= m; kv.z *= m; kv.w *= m;
        vv.x *= m; vv.y *= m; vv.z *= m; vv.w *= m;
        Ks[j] = kv;
        Vs[j] = vv;
        lnm += 1.f - m;
    }
    lnm = wave_sum(lnm);
    if ((tid & 63) == 0 && lnm != 0.f) atomicAdd(&nmask_s, lnm);
    __syncthreads();

    const int r = rb * RPB + (tid % RPB);
    const int ks = tid / RPB;
    const float inv_scale = 0.16439898730535729f;  // 1/sqrt(37)
    float4 qv = bf4_to_f4(base + (size_t)r * 96 + h * 4);
    qv.x *= inv_scale; qv.y *= inv_scale; qv.z *= inv_scale; qv.w *= inv_scale;

    float Sall = 0.f, ox = 0.f, oy = 0.f, oz = 0.f, ow = 0.f;
    constexpr int KC = T / KS;
    const int k0 = ks * KC;
    #pragma unroll 4
    for (int k = k0; k < k0 + KC; k++) {
        float4 kv = Ks[k];
        float4 vv = Vs[k];
        float s = fmaf(qv.x, kv.x, fmaf(qv.y, kv.y, fmaf(qv.z, kv.z, qv.w * kv.w)));
        float e = __expf(s);
        Sall += e;
        ox = fmaf(e, vv.x, ox);
        oy = fmaf(e, vv.y, oy);
        oz = fmaf(e, vv.z, oz);
        ow = fmaf(e, vv.w, ow);
    }
    if (ks > 0) {
        float* p = &part[((ks - 1) * RPB + (tid % RPB)) * 5];
        p[0] = Sall; p[1] = ox; p[2] = oy; p[3] = oz; p[4] = ow;
    }
    __syncthreads();
    if (ks == 0) {
        #pragma unroll
        for (int s2 = 0; s2 < KS - 1; s2++) {
            const float* p = &part[(s2 * RPB + r - rb * RPB) * 5];
            Sall += p[0]; ox += p[1]; oy += p[2]; oz += p[3]; ow += p[4];
        }
        float Sm = Sall - nmask_s;
        float inv = 1.f / (Sm + 1e-13f * Sall);
        __hip_bfloat16* op = o32 + (size_t)(b * T + r) * ATTD + h * 4;
        op[0] = __float2bfloat16(ox * inv);
        op[1] = __float2bfloat16(oy * inv);
        op[2] = __float2bfloat16(oz * inv);
        op[3] = __float2bfloat16(ow * inv);
    }
}

// ---------------- mix + L2 normalize (bf16 in/out) ----------------
__global__ __launch_bounds__(256) void mixnorm_bf(const __hip_bfloat16* __restrict__ x,
                                                  const __hip_bfloat16* __restrict__ xc,
                                                  const float* __restrict__ mask,
                                                  const float* __restrict__ mixer,
                                                  __hip_bfloat16* __restrict__ out) {
    int wid = (blockIdx.x * 256 + threadIdx.x) >> 6;
    int lane = threadIdx.x & 63;
    float mixv = mixer[0];
    float mval = mask[wid];
    const __hip_bfloat16* xr = x + (size_t)wid * EMB;
    const __hip_bfloat16* xcr = xc + (size_t)wid * EMB;
    float v[5];
    float s2 = 0.f;
    #pragma unroll
    for (int r = 0; r < 5; r++) {
        int idx = lane + r * 64;
        float val = 0.f;
        if (idx < EMB) val = (mixv * bf2f(xr[idx]) + (1.f - mixv) * bf2f(xcr[idx])) * mval;
        v[r] = val;
        s2 += val * val;
    }
    s2 = wave_sum(s2);
    float inv = 1.f / (sqrtf(s2) + 1e-13f);
    __hip_bfloat16* o = out + (size_t)wid * EMB;
    #pragma unroll
    for (int r = 0; r < 5; r++) {
        int idx = lane + r * 64;
        if (idx < EMB) o[idx] = __float2bfloat16(v[r] * inv);
    }
}

// ---------------- kernel pooling with grouped exp-recurrence ----------------
// For k>=1: mu_k = 0.95 - 0.1(k-1), sigma=0.1.  e_k = -50(c-mu_k)^2.
// e_{k+1} = e_k - 10(c-mu_k) - 0.5  => t *= r with r_{k+1} = r_k * e^-1.
// 4 groups of 5 kernels, each group re-anchored (bounds underflow drift).
__global__ __launch_bounds__(256) void pool_kernel(const float* __restrict__ Cos,
                                                   const float* __restrict__ mask_q,
                                                   const float* __restrict__ mask_d,
                                                   const float* __restrict__ nn_scaler,
                                                   float* __restrict__ lp) {
    int wid = (blockIdx.x * 256 + threadIdx.x) >> 6;
    int lane = threadIdx.x & 63;
    int b = wid >> 6, qi = wid & 63;
    const float* crow = Cos + ((size_t)b * LQ + qi) * LD;
    const float* md = mask_d + b * LD;
    float acc[NK];
    #pragma unroll
    for (int k = 0; k < NK; k++) acc[k] = 0.f;
    #pragma unroll
    for (int rr = 0; rr < LD / 64; rr++) {
        int dj = rr * 64 + lane;
        float m = md[dj];
        if (m != 0.f) {
            float cv = crow[dj];
            float d0 = cv - 1.0f;
            acc[0] += __expf(d0 * d0 * -500000.0f);
            #pragma unroll
            for (int g = 0; g < 4; g++) {
                float mu_a = 0.95f - 0.5f * g;
                float dc = cv - mu_a;
                float t = __expf(dc * dc * -50.0f);
                float r = __expf(fmaf(-10.0f, dc, -0.5f));
                #pragma unroll
                for (int j = 0; j < 5; j++) {
                    acc[1 + 5 * g + j] += t;
                    t *= r;
                    r *= 0.36787944117144233f;   // e^-1
                }
            }
        }
    }
    float mq = mask_q[b * LQ + qi];
    float ns = nn_scaler[0];
    #pragma unroll
    for (int k = 0; k < NK; k++) {
        float s = wave_sum(acc[k]);
        if (lane == 0) lp[((size_t)b * LQ + qi) * NK + k] = log2f(fmaxf(s, 1e-10f)) * ns * mq;
    }
}

// ---------------- final: out[b] = sum_k dense_w[k] * sum_qi lp[b,qi,k] ----------------
__global__ void final_kernel(const float* __restrict__ lp, const float* __restrict__ dense_w,
                             float* __restrict__ out) {
    int b = blockIdx.x;
    int t = threadIdx.x;  // 64 threads
    float s = 0.f;
    if (t < NK) {
        for (int qi = 0; qi < LQ; qi++) s += lp[((size_t)b * LQ + qi) * NK + t];
        s *= dense_w[t];
    }
    s = wave_sum(s);
    if (t == 0) out[b] = s;
}

extern "C" void kernel_launch(void* const* d_in, const int* in_sizes, int n_in,
                              void* d_out, int out_size, void* d_ws, size_t ws_size,
                              hipStream_t stream) {
    (void)in_sizes; (void)n_in; (void)out_size; (void)ws_size;
    const float* q_embed  = (const float*)d_in[0];
    const float* d_embed  = (const float*)d_in[1];
    const float* mask_q   = (const float*)d_in[2];
    const float* mask_d   = (const float*)d_in[3];
    const float* mixer    = (const float*)d_in[4];
    const float* nn_scaler= (const float*)d_in[5];
    const float* ff_w1    = (const float*)d_in[6];
    const float* ff_b1    = (const float*)d_in[7];
    const float* ff_w2    = (const float*)d_in[8];
    const float* ff_b2    = (const float*)d_in[9];
    const float* ln1_g    = (const float*)d_in[10];
    const float* ln1_b    = (const float*)d_in[11];
    const float* att_w    = (const float*)d_in[12];
    const float* att_b    = (const float*)d_in[13];
    const float* out_w    = (const float*)d_in[14];
    const float* out_b    = (const float*)d_in[15];
    const float* ln2_g    = (const float*)d_in[16];
    const float* ln2_b    = (const float*)d_in[17];
    const float* dense_w  = (const float*)d_in[18];
    float* out = (float*)d_out;

    // ---------------- workspace layout ----------------
    float* ws   = (float*)d_ws;
    float* cosb = ws;                         // 32*64*512 = 1,048,576 fp32
    float* lp   = cosb + 1048576;             // 43,008
    float* mall = lp + 43008;                 // 18,432
    __hip_bfloat16* xbf   = (__hip_bfloat16*)(mall + MALL);   // MALL*EMB (masked emb, persists)
    __hip_bfloat16* xcbf  = xbf  + (size_t)MALL * EMB;        // layer-0 output
    __hip_bfloat16* xc2bf = xcbf + (size_t)MALL * EMB;        // layer-1 output
    __hip_bfloat16* t2bf  = xc2bf + (size_t)MALL * EMB;       // FF2/OUT output (LN input)
    __hip_bfloat16* hbf   = t2bf + (size_t)MALL * EMB;        // LN1 out; later qdn
    __hip_bfloat16* t1bf  = hbf  + (size_t)MALL * EMB;        // MALL*FFH
    __hip_bfloat16* cbf   = t1bf + (size_t)MALL * FFH;        // MALL*96
    __hip_bfloat16* o32bf = cbf  + (size_t)MALL * 96;         // MALL*ATTD
    __hip_bfloat16* w1t   = o32bf + (size_t)MALL * ATTD;      // 2*100*300
    __hip_bfloat16* w2t   = w1t + 2 * FFH * EMB;              // 2*300*100
    __hip_bfloat16* awt   = w2t + 2 * EMB * FFH;              // 2*96*300
    __hip_bfloat16* owt   = awt + 2 * 96 * EMB;               // 2*300*32

    // 0. weights (bf16, transposed) in one kernel
    convert_all<<<(196800 + 255) / 256, 256, 0, stream>>>(ff_w1, ff_w2, att_w, out_w,
                                                          w1t, w2t, awt, owt);
    // 1. masked inputs (bf16) + concat masks in one kernel
    maskmul_all<<<(MALL * EMB + 255) / 256, 256, 0, stream>>>(q_embed, d_embed, mask_q, mask_d,
                                                              xbf, mall);

    // 2. merged encoder, bf16 stream throughout
    const __hip_bfloat16* xcur = xbf;
    for (int l = 0; l < 2; l++) {
        __hip_bfloat16* xout = (l == 0) ? xcbf : xc2bf;
        // FF1: relu(x @ w1 + b1) -> t1bf
        gemm_mfma<true, false><<<dim3(2, MALL / 64), 256, 0, stream>>>(
            xcur, w1t + (size_t)l * FFH * EMB, ff_b1 + l * FFH, nullptr,
            t1bf, MALL, FFH, EMB);
        // FF2: t1 @ w2 + b2 + x -> t2bf
        gemm_mfma<false, true><<<dim3(5, MALL / 64), 256, 0, stream>>>(
            t1bf, w2t + (size_t)l * EMB * FFH, ff_b2 + l * EMB, xcur,
            t2bf, MALL, EMB, FFH);
        // LN1 -> hbf
        ln_bf<<<MALL / 4, 256, 0, stream>>>(t2bf, ln1_g + l * EMB, ln1_b + l * EMB, hbf, MALL);
        // ATT: h @ att_w + att_b -> cbf
        gemm_mfma<false, false><<<dim3(2, MALL / 64), 256, 0, stream>>>(
            hbf, awt + (size_t)l * 96 * EMB, att_b + l * 96, nullptr,
            cbf, MALL, 96, EMB);
        // attention -> o32bf
        attn_fused<LQ, 64, 8><<<BATCH * NH, 512, 0, stream>>>(cbf, mask_q, o32bf);
        attn_fused<LD, 128, 4><<<BATCH * NH * (LD / 128), 512, 0, stream>>>(
            cbf + (size_t)MQ * 96, mask_d, o32bf + (size_t)MQ * ATTD);
        // OUT: o32 @ out_w + out_b + h -> t2bf
        gemm_mfma<false, true><<<dim3(5, MALL / 64), 256, 0, stream>>>(
            o32bf, owt + (size_t)l * EMB * ATTD, out_b + l * EMB, hbf,
            t2bf, MALL, EMB, ATTD);
        // LN2 -> xout
        ln_bf<<<MALL / 4, 256, 0, stream>>>(t2bf, ln2_g + l * EMB, ln2_b + l * EMB, xout, MALL);
        xcur = xout;
    }

    // 3. mix + normalize -> hbf (free after encoder)
    mixnorm_bf<<<MALL / 4, 256, 0, stream>>>(xbf, xc2bf, mall, mixer, hbf);

    // 4. cosine matrix via MFMA -> cosb
    cos_mfma<<<dim3(LD / 64, BATCH), 256, 0, stream>>>(hbf, hbf + (size_t)MQ * EMB, cosb);

    // 5. kernel pooling (grouped exp-recurrence)
    pool_kernel<<<(BATCH * LQ) / 4, 256, 0, stream>>>(cosb, mask_q, mask_d, nn_scaler, lp);

    // 6. final projection
    final_kernel<<<BATCH, 64, 0, stream>>>(lp, dense_w, out);
}

// Round 10
// 242.454 us; speedup vs baseline: 2.0948x; 1.0014x over previous
//
#include <hip/hip_runtime.h>
#include <hip/hip_bf16.h>

// Problem constants
#define BATCH 32
#define LQ 64
#define LD 512
#define EMB 300
#define FFH 100
#define ATTD 32
#define NH 8
#define NK 21
#define MQ (BATCH * LQ)          // 2048 query tokens
#define MD (BATCH * LD)          // 16384 doc tokens
#define MALL (MQ + MD)           // 18432 merged tokens

typedef __attribute__((ext_vector_type(8))) short bf16x8;
typedef __attribute__((ext_vector_type(4))) float f32x4;

__device__ __forceinline__ float wave_sum(float v) {
    #pragma unroll
    for (int off = 32; off > 0; off >>= 1) v += __shfl_xor(v, off);
    return v;
}

__device__ __forceinline__ float bf2f(__hip_bfloat16 h) {
    return __bfloat162float(h);
}

// 4 consecutive bf16 -> float4 (8B-aligned source)
__device__ __forceinline__ float4 bf4_to_f4(const __hip_bfloat16* p) {
    uint2 u = *(const uint2*)p;
    float4 f;
    f.x = __uint_as_float((u.x & 0xffffu) << 16);
    f.y = __uint_as_float(u.x & 0xffff0000u);
    f.z = __uint_as_float((u.y & 0xffffu) << 16);
    f.w = __uint_as_float(u.y & 0xffff0000u);
    return f;
}

// ---------------- fused input prep: xbf = bf16(emb*mask), mall = concat masks ------------
__global__ void maskmul_all(const float* __restrict__ q_embed, const float* __restrict__ d_embed,
                            const float* __restrict__ mask_q, const float* __restrict__ mask_d,
                            __hip_bfloat16* __restrict__ xbf, float* __restrict__ mall) {
    int i = blockIdx.x * blockDim.x + threadIdx.x;
    if (i >= MALL * EMB) return;
    int tok = i / EMB;
    float m, v;
    if (tok < MQ) {
        m = mask_q[tok];
        v = q_embed[i];
    } else {
        m = mask_d[tok - MQ];
        v = d_embed[i - MQ * EMB];
    }
    xbf[i] = __float2bfloat16(v * m);
    if (i % EMB == 0) mall[tok] = m;
}

// ---------------- all weights convert + transpose in one kernel ----------------
__device__ __forceinline__ void conv_seg(const float* __restrict__ w, __hip_bfloat16* __restrict__ wt,
                                         int j, int K, int N) {
    int l = j / (K * N);
    int r = j % (K * N);
    int k = r / N, n = r % N;
    wt[(size_t)l * N * K + (size_t)n * K + k] = __float2bfloat16(w[j]);
}
__global__ void convert_all(const float* __restrict__ w1, const float* __restrict__ w2,
                            const float* __restrict__ aw, const float* __restrict__ ow,
                            __hip_bfloat16* __restrict__ w1t, __hip_bfloat16* __restrict__ w2t,
                            __hip_bfloat16* __restrict__ awt, __hip_bfloat16* __restrict__ owt) {
    int i = blockIdx.x * blockDim.x + threadIdx.x;
    const int S1 = 2 * EMB * FFH;        // 60000
    const int S2 = S1 + 2 * FFH * EMB;   // 120000
    const int S3 = S2 + 2 * EMB * 96;    // 177600
    const int S4 = S3 + 2 * ATTD * EMB;  // 196800
    if (i < S1)       conv_seg(w1, w1t, i, EMB, FFH);
    else if (i < S2)  conv_seg(w2, w2t, i - S1, FFH, EMB);
    else if (i < S3)  conv_seg(aw, awt, i - S2, EMB, 96);
    else if (i < S4)  conv_seg(ow, owt, i - S3, ATTD, EMB);
}

// ---------------- shared staging helper: 8 bf16 of one row ----------------
__device__ __forceinline__ void stage_row8(const __hip_bfloat16* __restrict__ src, bool rowvalid,
                                           int K, int gk, __hip_bfloat16* dst) {
    if (rowvalid && gk + 8 <= K) {
        const uint2* p = (const uint2*)(src + gk);
        uint2 a = p[0], b = p[1];
        *(uint2*)dst = a;
        *(uint2*)(dst + 4) = b;
    } else {
        #pragma unroll
        for (int j = 0; j < 8; j++)
            dst[j] = (rowvalid && gk + j < K) ? src[gk + j] : __float2bfloat16(0.f);
    }
}

// ---------------- MFMA bf16 GEMM: Cb[M,N] = A[M,K] @ Bt[N,K]^T + bias (+relu) ----------
// 64x64 tile, 4 waves (2x2), each wave 32x32 via 2x2 mfma_f32_16x16x32_bf16 fragments.
// D layout (m89-verified): col = lane&15, row = (lane>>4)*4 + reg.
template <bool RELU>
__global__ __launch_bounds__(256) void gemm_mfma(const __hip_bfloat16* __restrict__ A,
                                                 const __hip_bfloat16* __restrict__ Bt,
                                                 const float* __restrict__ bias,
                                                 __hip_bfloat16* __restrict__ Cb,
                                                 int M, int N, int K) {
    __shared__ __align__(16) __hip_bfloat16 As[64][40];
    __shared__ __align__(16) __hip_bfloat16 Bs[64][40];
    const int tid = threadIdx.x;
    const int m0 = blockIdx.y * 64, n0 = blockIdx.x * 64;
    const int lane = tid & 63;
    const int wv = tid >> 6;
    const int wm = wv >> 1, wn = wv & 1;
    const int l15 = lane & 15, lg = lane >> 4;
    const int srow = tid >> 2, sk8 = (tid & 3) * 8;
    f32x4 acc[2][2] = {};
    const int NS = (K + 31) >> 5;
    const __hip_bfloat16* arow = A + (size_t)(m0 + srow) * K;
    const bool bvalid = (n0 + srow) < N;
    const __hip_bfloat16* brow = Bt + (size_t)(n0 + srow) * K;

    for (int s = 0; s < NS; s++) {
        const int gk = (s << 5) + sk8;
        if (s) __syncthreads();
        stage_row8(arow, true, K, gk, &As[srow][sk8]);
        stage_row8(brow, bvalid, K, gk, &Bs[srow][sk8]);
        __syncthreads();
        bf16x8 af0 = *(const bf16x8*)&As[wm * 32 + l15][lg * 8];
        bf16x8 af1 = *(const bf16x8*)&As[wm * 32 + 16 + l15][lg * 8];
        bf16x8 bf0 = *(const bf16x8*)&Bs[wn * 32 + l15][lg * 8];
        bf16x8 bf1 = *(const bf16x8*)&Bs[wn * 32 + 16 + l15][lg * 8];
        acc[0][0] = __builtin_amdgcn_mfma_f32_16x16x32_bf16(af0, bf0, acc[0][0], 0, 0, 0);
        acc[0][1] = __builtin_amdgcn_mfma_f32_16x16x32_bf16(af0, bf1, acc[0][1], 0, 0, 0);
        acc[1][0] = __builtin_amdgcn_mfma_f32_16x16x32_bf16(af1, bf0, acc[1][0], 0, 0, 0);
        acc[1][1] = __builtin_amdgcn_mfma_f32_16x16x32_bf16(af1, bf1, acc[1][1], 0, 0, 0);
    }

    #pragma unroll
    for (int fc = 0; fc < 2; fc++) {
        int col = n0 + wn * 32 + fc * 16 + l15;
        if (col >= N) continue;
        float bs = bias[col];
        #pragma unroll
        for (int fr = 0; fr < 2; fr++) {
            int rbase = m0 + wm * 32 + fr * 16 + lg * 4;
            #pragma unroll
            for (int r = 0; r < 4; r++) {
                int row = rbase + r;
                float v = acc[fr][fc][r] + bs;
                if (RELU) v = fmaxf(v, 0.f);
                Cb[(size_t)row * N + col] = __float2bfloat16(v);
            }
        }
    }
}

// ---------------- FUSED GEMM + residual + LayerNorm (N = EMB = 300 fixed) ---------------
// Y = LN( A[M,K] @ Bt[300,K]^T + bias + Res ), row-complete per block.
// Block: 256 thr = 4 waves; 32 rows/block; wave wv covers cols [wv*80, wv*80+80) (5 frags).
// LN stats: two-pass; 16-lane shuffle reduce (cols of a row live in one l15 group) +
// cross-wave combine via LDS. ddof=1, eps added to std.
__global__ __launch_bounds__(256) void gemm_ln(const __hip_bfloat16* __restrict__ A,
                                               const __hip_bfloat16* __restrict__ Bt,
                                               const float* __restrict__ bias,
                                               const __hip_bfloat16* __restrict__ Res,
                                               const float* __restrict__ g,
                                               const float* __restrict__ beta,
                                               __hip_bfloat16* __restrict__ Y,
                                               int M, int K) {
    __shared__ __align__(16) __hip_bfloat16 As[32][40];
    __shared__ __align__(16) __hip_bfloat16 Bs[320][40];
    __shared__ float red[2][4][32];
    const int tid = threadIdx.x;
    const int m0 = blockIdx.x * 32;
    const int lane = tid & 63;
    const int wv = tid >> 6;
    const int l15 = lane & 15, lg = lane >> 4;
    const int c0 = wv * 80;
    f32x4 acc[2][5] = {};
    const int NS = (K + 31) >> 5;

    for (int s = 0; s < NS; s++) {
        const int gk0 = s << 5;
        if (s) __syncthreads();
        for (int ch = tid; ch < 1408; ch += 256) {
            if (ch < 128) {
                int row = ch >> 2, k8 = (ch & 3) * 8;
                stage_row8(A + (size_t)(m0 + row) * K, true, K, gk0 + k8, &As[row][k8]);
            } else {
                int cc = ch - 128;
                int row = cc >> 2, k8 = (cc & 3) * 8;
                stage_row8(Bt + (size_t)row * K, row < EMB, K, gk0 + k8, &Bs[row][k8]);
            }
        }
        __syncthreads();
        bf16x8 af[2], bfr[5];
        af[0] = *(const bf16x8*)&As[l15][lg * 8];
        af[1] = *(const bf16x8*)&As[16 + l15][lg * 8];
        #pragma unroll
        for (int fc = 0; fc < 5; fc++)
            bfr[fc] = *(const bf16x8*)&Bs[c0 + fc * 16 + l15][lg * 8];
        #pragma unroll
        for (int fr = 0; fr < 2; fr++)
            #pragma unroll
            for (int fc = 0; fc < 5; fc++)
                acc[fr][fc] = __builtin_amdgcn_mfma_f32_16x16x32_bf16(af[fr], bfr[fc], acc[fr][fc], 0, 0, 0);
    }

    // epilogue pass 1: v = acc + bias + res (in place); per-row sums over this wave's cols
    float rs[2][4];
    #pragma unroll
    for (int fr = 0; fr < 2; fr++)
        #pragma unroll
        for (int r = 0; r < 4; r++) rs[fr][r] = 0.f;
    #pragma unroll
    for (int fc = 0; fc < 5; fc++) {
        int col = c0 + fc * 16 + l15;
        bool valid = col < EMB;
        float bs = valid ? bias[col] : 0.f;
        #pragma unroll
        for (int fr = 0; fr < 2; fr++) {
            int rowb = m0 + fr * 16 + lg * 4;
            #pragma unroll
            for (int r = 0; r < 4; r++) {
                float v = 0.f;
                if (valid) v = acc[fr][fc][r] + bs + bf2f(Res[(size_t)(rowb + r) * EMB + col]);
                acc[fr][fc][r] = v;
                rs[fr][r] += v;
            }
        }
    }
    #pragma unroll
    for (int fr = 0; fr < 2; fr++)
        #pragma unroll
        for (int r = 0; r < 4; r++)
            #pragma unroll
            for (int off = 1; off < 16; off <<= 1)
                rs[fr][r] += __shfl_xor(rs[fr][r], off);
    if (l15 == 0) {
        #pragma unroll
        for (int fr = 0; fr < 2; fr++)
            #pragma unroll
            for (int r = 0; r < 4; r++)
                red[0][wv][fr * 16 + lg * 4 + r] = rs[fr][r];
    }
    __syncthreads();
    float mean[2][4];
    #pragma unroll
    for (int fr = 0; fr < 2; fr++)
        #pragma unroll
        for (int r = 0; r < 4; r++) {
            int ri = fr * 16 + lg * 4 + r;
            mean[fr][r] = (red[0][0][ri] + red[0][1][ri] + red[0][2][ri] + red[0][3][ri]) * (1.f / EMB);
        }
    // pass 2: sum of squared deviations
    float rq[2][4];
    #pragma unroll
    for (int fr = 0; fr < 2; fr++)
        #pragma unroll
        for (int r = 0; r < 4; r++) rq[fr][r] = 0.f;
    #pragma unroll
    for (int fc = 0; fc < 5; fc++) {
        int col = c0 + fc * 16 + l15;
        bool valid = col < EMB;
        #pragma unroll
        for (int fr = 0; fr < 2; fr++)
            #pragma unroll
            for (int r = 0; r < 4; r++) {
                if (valid) {
                    float d = acc[fr][fc][r] - mean[fr][r];
                    rq[fr][r] += d * d;
                }
            }
    }
    #pragma unroll
    for (int fr = 0; fr < 2; fr++)
        #pragma unroll
        for (int r = 0; r < 4; r++)
            #pragma unroll
            for (int off = 1; off < 16; off <<= 1)
                rq[fr][r] += __shfl_xor(rq[fr][r], off);
    if (l15 == 0) {
        #pragma unroll
        for (int fr = 0; fr < 2; fr++)
            #pragma unroll
            for (int r = 0; r < 4; r++)
                red[1][wv][fr * 16 + lg * 4 + r] = rq[fr][r];
    }
    __syncthreads();
    float inv[2][4];
    #pragma unroll
    for (int fr = 0; fr < 2; fr++)
        #pragma unroll
        for (int r = 0; r < 4; r++) {
            int ri = fr * 16 + lg * 4 + r;
            float tot = red[1][0][ri] + red[1][1][ri] + red[1][2][ri] + red[1][3][ri];
            float stdv = sqrtf(tot * (1.f / (EMB - 1)));
            inv[fr][r] = 1.f / (stdv + 1e-6f);
        }
    // write: y = g*(v-mean)*inv + beta
    #pragma unroll
    for (int fc = 0; fc < 5; fc++) {
        int col = c0 + fc * 16 + l15;
        if (col >= EMB) continue;
        float gv = g[col], bv = beta[col];
        #pragma unroll
        for (int fr = 0; fr < 2; fr++) {
            int rowb = m0 + fr * 16 + lg * 4;
            #pragma unroll
            for (int r = 0; r < 4; r++) {
                float y = gv * (acc[fr][fc][r] - mean[fr][r]) * inv[fr][r] + bv;
                Y[(size_t)(rowb + r) * EMB + col] = __float2bfloat16(y);
            }
        }
    }
}

// ---------------- attention body (templated), smem carved by caller ----------------
template <int T, int RPB, int KS>
__device__ __forceinline__ void attn_body(const __hip_bfloat16* __restrict__ cseg,
                                          const float* __restrict__ mask,
                                          __hip_bfloat16* __restrict__ oseg,
                                          int bh, int rb, char* smem) {
    constexpr int BLK = 512;
    float4* Ks = (float4*)smem;
    float4* Vs = Ks + T;
    float* part = (float*)(Vs + T);
    float* nmask_s = part + RPB * 5 * (KS - 1);
    const int b = bh / NH, h = bh % NH;
    const int tid = threadIdx.x;
    const __hip_bfloat16* base = cseg + (size_t)b * T * 96;

    if (tid == 0) *nmask_s = 0.f;
    __syncthreads();
    float lnm = 0.f;
    for (int j = tid; j < T; j += BLK) {
        float m = mask[b * T + j];
        float4 kv = bf4_to_f4(base + (size_t)j * 96 + ATTD + h * 4);
        float4 vv = bf4_to_f4(base + (size_t)j * 96 + 2 * ATTD + h * 4);
        kv.x *= m; kv.y *= m; kv.z *= m; kv.w *= m;
        vv.x *= m; vv.y *= m; vv.z *= m; vv.w *= m;
        Ks[j] = kv;
        Vs[j] = vv;
        lnm += 1.f - m;
    }
    lnm = wave_sum(lnm);
    if ((tid & 63) == 0 && lnm != 0.f) atomicAdd(nmask_s, lnm);
    __syncthreads();

    const int r = rb * RPB + (tid % RPB);
    const int ks = tid / RPB;
    const float inv_scale = 0.16439898730535729f;  // 1/sqrt(37)
    float4 qv = bf4_to_f4(base + (size_t)r * 96 + h * 4);
    qv.x *= inv_scale; qv.y *= inv_scale; qv.z *= inv_scale; qv.w *= inv_scale;

    float Sall = 0.f, ox = 0.f, oy = 0.f, oz = 0.f, ow = 0.f;
    constexpr int KC = T / KS;
    const int k0 = ks * KC;
    #pragma unroll 4
    for (int k = k0; k < k0 + KC; k++) {
        float4 kv = Ks[k];
        float4 vv = Vs[k];
        float s = fmaf(qv.x, kv.x, fmaf(qv.y, kv.y, fmaf(qv.z, kv.z, qv.w * kv.w)));
        float e = __expf(s);
        Sall += e;
        ox = fmaf(e, vv.x, ox);
        oy = fmaf(e, vv.y, oy);
        oz = fmaf(e, vv.z, oz);
        ow = fmaf(e, vv.w, ow);
    }
    if (ks > 0) {
        float* p = &part[((ks - 1) * RPB + (tid % RPB)) * 5];
        p[0] = Sall; p[1] = ox; p[2] = oy; p[3] = oz; p[4] = ow;
    }
    __syncthreads();
    if (ks == 0) {
        #pragma unroll
        for (int s2 = 0; s2 < KS - 1; s2++) {
            const float* p = &part[(s2 * RPB + r - rb * RPB) * 5];
            Sall += p[0]; ox += p[1]; oy += p[2]; oz += p[3]; ow += p[4];
        }
        float Sm = Sall - *nmask_s;
        float inv = 1.f / (Sm + 1e-13f * Sall);
        __hip_bfloat16* op = oseg + (size_t)(b * T + r) * ATTD + h * 4;
        op[0] = __float2bfloat16(ox * inv);
        op[1] = __float2bfloat16(oy * inv);
        op[2] = __float2bfloat16(oz * inv);
        op[3] = __float2bfloat16(ow * inv);
    }
}

// ---------------- merged q+d attention: blocks [0,256) = q, [256,1280) = d ----------------
__global__ __launch_bounds__(512) void attn_both(const __hip_bfloat16* __restrict__ cbf,
                                                 const float* __restrict__ mask_q,
                                                 const float* __restrict__ mask_d,
                                                 __hip_bfloat16* __restrict__ o32) {
    __shared__ __align__(16) char smem[24576];
    int blk = blockIdx.x;
    if (blk < BATCH * NH) {
        attn_body<LQ, 64, 8>(cbf, mask_q, o32, blk, 0, smem);
    } else {
        int bid = blk - BATCH * NH;
        attn_body<LD, 128, 4>(cbf + (size_t)MQ * 96, mask_d, o32 + (size_t)MQ * ATTD,
                              bid >> 2, bid & 3, smem);
    }
}

// ---------------- batched MFMA cos GEMM: Cos[b] = Qn[b] (64xK) @ Dn[b] (512xK)^T (fp32 out)
__global__ __launch_bounds__(256) void cos_mfma(const __hip_bfloat16* __restrict__ Qn,
                                                const __hip_bfloat16* __restrict__ Dn,
                                                float* __restrict__ Cos) {
    __shared__ __align__(16) __hip_bfloat16 As[64][40];
    __shared__ __align__(16) __hip_bfloat16 Bs[64][40];
    const int b = blockIdx.y;
    const int n0 = blockIdx.x * 64;
    const int tid = threadIdx.x;
    const int lane = tid & 63;
    const int wv = tid >> 6;
    const int wm = wv >> 1, wn = wv & 1;
    const int l15 = lane & 15, lg = lane >> 4;
    const int srow = tid >> 2, sk8 = (tid & 3) * 8;
    f32x4 acc[2][2] = {};
    const int NS = (EMB + 31) >> 5;   // 10
    const __hip_bfloat16* arow = Qn + ((size_t)b * LQ + srow) * EMB;
    const __hip_bfloat16* brow = Dn + ((size_t)b * LD + n0 + srow) * EMB;

    for (int s = 0; s < NS; s++) {
        const int gk = (s << 5) + sk8;
        if (s) __syncthreads();
        stage_row8(arow, true, EMB, gk, &As[srow][sk8]);
        stage_row8(brow, true, EMB, gk, &Bs[srow][sk8]);
        __syncthreads();
        bf16x8 af0 = *(const bf16x8*)&As[wm * 32 + l15][lg * 8];
        bf16x8 af1 = *(const bf16x8*)&As[wm * 32 + 16 + l15][lg * 8];
        bf16x8 bf0 = *(const bf16x8*)&Bs[wn * 32 + l15][lg * 8];
        bf16x8 bf1 = *(const bf16x8*)&Bs[wn * 32 + 16 + l15][lg * 8];
        acc[0][0] = __builtin_amdgcn_mfma_f32_16x16x32_bf16(af0, bf0, acc[0][0], 0, 0, 0);
        acc[0][1] = __builtin_amdgcn_mfma_f32_16x16x32_bf16(af0, bf1, acc[0][1], 0, 0, 0);
        acc[1][0] = __builtin_amdgcn_mfma_f32_16x16x32_bf16(af1, bf0, acc[1][0], 0, 0, 0);
        acc[1][1] = __builtin_amdgcn_mfma_f32_16x16x32_bf16(af1, bf1, acc[1][1], 0, 0, 0);
    }

    float* cb = Cos + (size_t)b * LQ * LD;
    #pragma unroll
    for (int fc = 0; fc < 2; fc++) {
        int col = n0 + wn * 32 + fc * 16 + l15;
        #pragma unroll
        for (int fr = 0; fr < 2; fr++) {
            int rbase = wm * 32 + fr * 16 + lg * 4;
            #pragma unroll
            for (int r = 0; r < 4; r++) {
                cb[(size_t)(rbase + r) * LD + col] = acc[fr][fc][r];
            }
        }
    }
}

// ---------------- mix + L2 normalize (bf16 in/out) ----------------
__global__ __launch_bounds__(256) void mixnorm_bf(const __hip_bfloat16* __restrict__ x,
                                                  const __hip_bfloat16* __restrict__ xc,
                                                  const float* __restrict__ mask,
                                                  const float* __restrict__ mixer,
                                                  __hip_bfloat16* __restrict__ out) {
    int wid = (blockIdx.x * 256 + threadIdx.x) >> 6;
    int lane = threadIdx.x & 63;
    float mixv = mixer[0];
    float mval = mask[wid];
    const __hip_bfloat16* xr = x + (size_t)wid * EMB;
    const __hip_bfloat16* xcr = xc + (size_t)wid * EMB;
    float v[5];
    float s2 = 0.f;
    #pragma unroll
    for (int r = 0; r < 5; r++) {
        int idx = lane + r * 64;
        float val = 0.f;
        if (idx < EMB) val = (mixv * bf2f(xr[idx]) + (1.f - mixv) * bf2f(xcr[idx])) * mval;
        v[r] = val;
        s2 += val * val;
    }
    s2 = wave_sum(s2);
    float inv = 1.f / (sqrtf(s2) + 1e-13f);
    __hip_bfloat16* o = out + (size_t)wid * EMB;
    #pragma unroll
    for (int r = 0; r < 5; r++) {
        int idx = lane + r * 64;
        if (idx < EMB) o[idx] = __float2bfloat16(v[r] * inv);
    }
}

// ---------------- kernel pooling with grouped exp-recurrence ----------------
__global__ __launch_bounds__(256) void pool_kernel(const float* __restrict__ Cos,
                                                   const float* __restrict__ mask_q,
                                                   const float* __restrict__ mask_d,
                                                   const float* __restrict__ nn_scaler,
                                                   float* __restrict__ lp) {
    int wid = (blockIdx.x * 256 + threadIdx.x) >> 6;
    int lane = threadIdx.x & 63;
    int b = wid >> 6, qi = wid & 63;
    const float* crow = Cos + ((size_t)b * LQ + qi) * LD;
    const float* md = mask_d + b * LD;
    float acc[NK];
    #pragma unroll
    for (int k = 0; k < NK; k++) acc[k] = 0.f;
    #pragma unroll
    for (int rr = 0; rr < LD / 64; rr++) {
        int dj = rr * 64 + lane;
        float m = md[dj];
        if (m != 0.f) {
            float cv = crow[dj];
            float d0 = cv - 1.0f;
            acc[0] += __expf(d0 * d0 * -500000.0f);
            #pragma unroll
            for (int g = 0; g < 4; g++) {
                float mu_a = 0.95f - 0.5f * g;
                float dc = cv - mu_a;
                float t = __expf(dc * dc * -50.0f);
                float r = __expf(fmaf(-10.0f, dc, -0.5f));
                #pragma unroll
                for (int j = 0; j < 5; j++) {
                    acc[1 + 5 * g + j] += t;
                    t *= r;
                    r *= 0.36787944117144233f;   // e^-1
                }
            }
        }
    }
    float mq = mask_q[b * LQ + qi];
    float ns = nn_scaler[0];
    #pragma unroll
    for (int k = 0; k < NK; k++) {
        float s = wave_sum(acc[k]);
        if (lane == 0) lp[((size_t)b * LQ + qi) * NK + k] = log2f(fmaxf(s, 1e-10f)) * ns * mq;
    }
}

// ---------------- final: out[b] = sum_k dense_w[k] * sum_qi lp[b,qi,k] ----------------
__global__ void final_kernel(const float* __restrict__ lp, const float* __restrict__ dense_w,
                             float* __restrict__ out) {
    int b = blockIdx.x;
    int t = threadIdx.x;  // 64 threads
    float s = 0.f;
    if (t < NK) {
        for (int qi = 0; qi < LQ; qi++) s += lp[((size_t)b * LQ + qi) * NK + t];
        s *= dense_w[t];
    }
    s = wave_sum(s);
    if (t == 0) out[b] = s;
}

extern "C" void kernel_launch(void* const* d_in, const int* in_sizes, int n_in,
                              void* d_out, int out_size, void* d_ws, size_t ws_size,
                              hipStream_t stream) {
    (void)in_sizes; (void)n_in; (void)out_size; (void)ws_size;
    const float* q_embed  = (const float*)d_in[0];
    const float* d_embed  = (const float*)d_in[1];
    const float* mask_q   = (const float*)d_in[2];
    const float* mask_d   = (const float*)d_in[3];
    const float* mixer    = (const float*)d_in[4];
    const float* nn_scaler= (const float*)d_in[5];
    const float* ff_w1    = (const float*)d_in[6];
    const float* ff_b1    = (const float*)d_in[7];
    const float* ff_w2    = (const float*)d_in[8];
    const float* ff_b2    = (const float*)d_in[9];
    const float* ln1_g    = (const float*)d_in[10];
    const float* ln1_b    = (const float*)d_in[11];
    const float* att_w    = (const float*)d_in[12];
    const float* att_b    = (const float*)d_in[13];
    const float* out_w    = (const float*)d_in[14];
    const float* out_b    = (const float*)d_in[15];
    const float* ln2_g    = (const float*)d_in[16];
    const float* ln2_b    = (const float*)d_in[17];
    const float* dense_w  = (const float*)d_in[18];
    float* out = (float*)d_out;

    // ---------------- workspace layout ----------------
    float* ws   = (float*)d_ws;
    float* cosb = ws;                         // 32*64*512 = 1,048,576 fp32
    float* lp   = cosb + 1048576;             // 43,008
    float* mall = lp + 43008;                 // 18,432
    __hip_bfloat16* xbf   = (__hip_bfloat16*)(mall + MALL);   // MALL*EMB (masked emb, persists)
    __hip_bfloat16* xcbf  = xbf  + (size_t)MALL * EMB;        // layer-0 output
    __hip_bfloat16* xc2bf = xcbf + (size_t)MALL * EMB;        // layer-1 output
    __hip_bfloat16* hbf   = xc2bf + (size_t)MALL * EMB;       // LN1 out; later qdn
    __hip_bfloat16* t1bf  = hbf  + (size_t)MALL * EMB;        // MALL*FFH
    __hip_bfloat16* cbf   = t1bf + (size_t)MALL * FFH;        // MALL*96
    __hip_bfloat16* o32bf = cbf  + (size_t)MALL * 96;         // MALL*ATTD
    __hip_bfloat16* w1t   = o32bf + (size_t)MALL * ATTD;      // 2*100*300
    __hip_bfloat16* w2t   = w1t + 2 * FFH * EMB;              // 2*300*100
    __hip_bfloat16* awt   = w2t + 2 * EMB * FFH;              // 2*96*300
    __hip_bfloat16* owt   = awt + 2 * 96 * EMB;               // 2*300*32

    // 0. weights (bf16, transposed) in one kernel
    convert_all<<<(196800 + 255) / 256, 256, 0, stream>>>(ff_w1, ff_w2, att_w, out_w,
                                                          w1t, w2t, awt, owt);
    // 1. masked inputs (bf16) + concat masks in one kernel
    maskmul_all<<<(MALL * EMB + 255) / 256, 256, 0, stream>>>(q_embed, d_embed, mask_q, mask_d,
                                                              xbf, mall);

    // 2. merged encoder, bf16 stream; FF2+LN1 and OUT+LN2 fused
    const __hip_bfloat16* xcur = xbf;
    for (int l = 0; l < 2; l++) {
        __hip_bfloat16* xout = (l == 0) ? xcbf : xc2bf;
        // FF1: relu(x @ w1 + b1) -> t1bf
        gemm_mfma<true><<<dim3(2, MALL / 64), 256, 0, stream>>>(
            xcur, w1t + (size_t)l * FFH * EMB, ff_b1 + l * FFH, t1bf, MALL, FFH, EMB);
        // FF2 + residual(x) + LN1 -> hbf
        gemm_ln<<<MALL / 32, 256, 0, stream>>>(
            t1bf, w2t + (size_t)l * EMB * FFH, ff_b2 + l * EMB, xcur,
            ln1_g + l * EMB, ln1_b + l * EMB, hbf, MALL, FFH);
        // ATT: h @ att_w + att_b -> cbf
        gemm_mfma<false><<<dim3(2, MALL / 64), 256, 0, stream>>>(
            hbf, awt + (size_t)l * 96 * EMB, att_b + l * 96, cbf, MALL, 96, EMB);
        // attention (q + d merged) -> o32bf
        attn_both<<<BATCH * NH + BATCH * NH * (LD / 128), 512, 0, stream>>>(
            cbf, mask_q, mask_d, o32bf);
        // OUT + residual(h) + LN2 -> xout
        gemm_ln<<<MALL / 32, 256, 0, stream>>>(
            o32bf, owt + (size_t)l * EMB * ATTD, out_b + l * EMB, hbf,
            ln2_g + l * EMB, ln2_b + l * EMB, xout, MALL, ATTD);
        xcur = xout;
    }

    // 3. mix + normalize -> hbf (free after encoder)
    mixnorm_bf<<<MALL / 4, 256, 0, stream>>>(xbf, xc2bf, mall, mixer, hbf);

    // 4. cosine matrix via MFMA -> cosb
    cos_mfma<<<dim3(LD / 64, BATCH), 256, 0, stream>>>(hbf, hbf + (size_t)MQ * EMB, cosb);

    // 5. kernel pooling (grouped exp-recurrence)
    pool_kernel<<<(BATCH * LQ) / 4, 256, 0, stream>>>(cosb, mask_q, mask_d, nn_scaler, lp);

    // 6. final projection
    final_kernel<<<BATCH, 64, 0, stream>>>(lp, dense_w, out);
}